// Round 1
// baseline (2865.815 us; speedup 1.0000x reference)
//
#include <hip/hip_runtime.h>
#include <hip/hip_bf16.h>
#include <cstdint>
#include <cstddef>

// ---------------------------------------------------------------------------
// GraphAutoEncoder: 3x TAGConv(K=3) + linear + bilinear decode, fp32 baseline.
// N=10000 nodes, E=320000 edges, D: 256 -> 128 -> 128 -> 64.
// ---------------------------------------------------------------------------

__global__ void count_kernel(const int* __restrict__ dst, int* __restrict__ counts, int E) {
    int e = blockIdx.x * blockDim.x + threadIdx.x;
    if (e < E) atomicAdd(&counts[dst[e]], 1);
}

__global__ void dis_kernel(const int* __restrict__ counts, float* __restrict__ dis, int n) {
    int i = blockIdx.x * blockDim.x + threadIdx.x;
    if (i < n) {
        int c = counts[i];
        dis[i] = (c > 0) ? rsqrtf((float)c) : 0.f;
    }
}

__global__ void norm_kernel(const int* __restrict__ src, const int* __restrict__ dst,
                            const float* __restrict__ dis, float* __restrict__ nrm, int E) {
    int e = blockIdx.x * blockDim.x + threadIdx.x;
    if (e < E) nrm[e] = dis[src[e]] * dis[dst[e]];
}

// single-block exclusive scan over counts[n] -> rowstart[n+1]
__global__ void scan_kernel(const int* __restrict__ counts, int* __restrict__ rowstart, int n) {
    __shared__ int sums[1024];
    int t = threadIdx.x;
    int chunk = (n + 1023) / 1024;
    int base = t * chunk;
    int s = 0;
    for (int i = 0; i < chunk; ++i) {
        int idx = base + i;
        if (idx < n) s += counts[idx];
    }
    sums[t] = s;
    __syncthreads();
    for (int off = 1; off < 1024; off <<= 1) {
        int v = (t >= off) ? sums[t - off] : 0;
        __syncthreads();
        sums[t] += v;
        __syncthreads();
    }
    int run = sums[t] - s;   // exclusive prefix of this thread's chunk
    for (int i = 0; i < chunk; ++i) {
        int idx = base + i;
        if (idx < n) { rowstart[idx] = run; run += counts[idx]; }
    }
    if (t == 1023) rowstart[n] = sums[1023];
}

__global__ void csr_fill_kernel(const int* __restrict__ src, const int* __restrict__ dst,
                                const float* __restrict__ nrm, const int* __restrict__ rowstart,
                                int* __restrict__ cursor, int* __restrict__ csr_src,
                                float* __restrict__ csr_w, int E) {
    int e = blockIdx.x * blockDim.x + threadIdx.x;
    if (e < E) {
        int d = dst[e];
        int pos = rowstart[d] + atomicAdd(&cursor[d], 1);
        csr_src[pos] = src[e];
        csr_w[pos]   = nrm[e];
    }
}

// out[n][t] = sum_{edges e with dst=n} w_e * h[src_e][t]; blockDim.x == D
__global__ void agg_kernel(const float* __restrict__ h, const int* __restrict__ rowstart,
                           const int* __restrict__ csr_src, const float* __restrict__ csr_w,
                           float* __restrict__ out, int D) {
    int n = blockIdx.x;
    int t = threadIdx.x;
    int beg = rowstart[n], end = rowstart[n + 1];
    float acc = 0.f;
    for (int j = beg; j < end; ++j) {
        acc += csr_w[j] * h[(size_t)csr_src[j] * D + t];
    }
    out[(size_t)n * D + t] = acc;
}

// C[M,Nc] (+)= A[M,K] @ B[K,Nc]; 64x64 tile, BK=32, 4x4 micro-tile.
// Nc multiple of 64, K multiple of 32; M guarded.
template <bool ACCUM, bool BIAS, bool RELU>
__global__ __launch_bounds__(256) void gemm_kernel(
        const float* __restrict__ A, const float* __restrict__ B,
        const float* __restrict__ bias, float* __restrict__ C,
        int M, int Nc, int K) {
    __shared__ float As[32][68];  // As[k][m]
    __shared__ float Bs[32][68];  // Bs[k][n]
    int bm0 = blockIdx.y * 64;
    int bn0 = blockIdx.x * 64;
    int tid = threadIdx.x;
    int ty = tid / 16, tx = tid % 16;
    float acc[4][4] = {};

    for (int kk0 = 0; kk0 < K; kk0 += 32) {
        {
            int r  = tid / 4;             // 0..63
            int k0 = (tid % 4) * 8;       // 0..24
            bool va = (bm0 + r) < M;
            const float* pa = A + (size_t)(bm0 + r) * K + kk0 + k0;
            #pragma unroll
            for (int k = 0; k < 8; ++k) As[k0 + k][r] = va ? pa[k] : 0.f;

            int kb = tid / 8;             // 0..31
            int c0 = (tid % 8) * 8;       // 0..56
            const float* pb = B + (size_t)(kk0 + kb) * Nc + bn0 + c0;
            #pragma unroll
            for (int c = 0; c < 8; ++c) Bs[kb][c0 + c] = pb[c];
        }
        __syncthreads();
        #pragma unroll
        for (int k = 0; k < 32; ++k) {
            float4 a = *(const float4*)&As[k][ty * 4];
            float4 b = *(const float4*)&Bs[k][tx * 4];
            acc[0][0] += a.x * b.x; acc[0][1] += a.x * b.y; acc[0][2] += a.x * b.z; acc[0][3] += a.x * b.w;
            acc[1][0] += a.y * b.x; acc[1][1] += a.y * b.y; acc[1][2] += a.y * b.z; acc[1][3] += a.y * b.w;
            acc[2][0] += a.z * b.x; acc[2][1] += a.z * b.y; acc[2][2] += a.z * b.z; acc[2][3] += a.z * b.w;
            acc[3][0] += a.w * b.x; acc[3][1] += a.w * b.y; acc[3][2] += a.w * b.z; acc[3][3] += a.w * b.w;
        }
        __syncthreads();
    }

    int row0 = bm0 + ty * 4;
    int col0 = bn0 + tx * 4;
    #pragma unroll
    for (int i = 0; i < 4; ++i) {
        int row = row0 + i;
        if (row < M) {
            float* cp = &C[(size_t)row * Nc + col0];
            float v0 = acc[i][0], v1 = acc[i][1], v2 = acc[i][2], v3 = acc[i][3];
            if (ACCUM) {
                float4 c = *(const float4*)cp;
                v0 += c.x; v1 += c.y; v2 += c.z; v3 += c.w;
            }
            if (BIAS) {
                v0 += bias[col0 + 0]; v1 += bias[col0 + 1];
                v2 += bias[col0 + 2]; v3 += bias[col0 + 3];
            }
            if (RELU) {
                v0 = fmaxf(v0, 0.f); v1 = fmaxf(v1, 0.f);
                v2 = fmaxf(v2, 0.f); v3 = fmaxf(v3, 0.f);
            }
            float4 v = make_float4(v0, v1, v2, v3);
            *(float4*)cp = v;
        }
    }
}

// adj[i][j] = sum_k zw[i][k] * z[j][k]; K=64. 64x64 tile, 4x4 micro-tile.
__global__ __launch_bounds__(256) void decode_kernel(
        const float* __restrict__ ZW, const float* __restrict__ Z,
        float* __restrict__ out, int Nn) {
    __shared__ float Sa[64][68];  // Sa[k][r] = ZW[bm0+r][k]
    __shared__ float Sb[64][68];  // Sb[k][c] = Z [bn0+c][k]
    int bm0 = blockIdx.y * 64;
    int bn0 = blockIdx.x * 64;
    int tid = threadIdx.x;
    {
        int r  = tid / 4;           // 0..63
        int k0 = (tid % 4) * 16;    // 0,16,32,48
        bool va = (bm0 + r) < Nn;
        bool vb = (bn0 + r) < Nn;
        const float* pa = ZW + (size_t)(bm0 + r) * 64 + k0;
        const float* pb = Z  + (size_t)(bn0 + r) * 64 + k0;
        #pragma unroll
        for (int k = 0; k < 16; ++k) {
            Sa[k0 + k][r] = va ? pa[k] : 0.f;
            Sb[k0 + k][r] = vb ? pb[k] : 0.f;
        }
    }
    __syncthreads();
    int ty = tid / 16, tx = tid % 16;
    float acc[4][4] = {};
    #pragma unroll
    for (int k = 0; k < 64; ++k) {
        float4 a = *(const float4*)&Sa[k][ty * 4];
        float4 b = *(const float4*)&Sb[k][tx * 4];
        acc[0][0] += a.x * b.x; acc[0][1] += a.x * b.y; acc[0][2] += a.x * b.z; acc[0][3] += a.x * b.w;
        acc[1][0] += a.y * b.x; acc[1][1] += a.y * b.y; acc[1][2] += a.y * b.z; acc[1][3] += a.y * b.w;
        acc[2][0] += a.z * b.x; acc[2][1] += a.z * b.y; acc[2][2] += a.z * b.z; acc[2][3] += a.z * b.w;
        acc[3][0] += a.w * b.x; acc[3][1] += a.w * b.y; acc[3][2] += a.w * b.z; acc[3][3] += a.w * b.w;
    }
    int row0 = bm0 + ty * 4;
    int col0 = bn0 + tx * 4;
    if (col0 < Nn) {
        #pragma unroll
        for (int i = 0; i < 4; ++i) {
            int row = row0 + i;
            if (row < Nn) {
                float4 v = make_float4(acc[i][0], acc[i][1], acc[i][2], acc[i][3]);
                *(float4*)&out[(size_t)row * Nn + col0] = v;
            }
        }
    }
}

extern "C" void kernel_launch(void* const* d_in, const int* in_sizes, int n_in,
                              void* d_out, int out_size, void* d_ws, size_t ws_size,
                              hipStream_t stream) {
    const float* x  = (const float*)d_in[0];
    const int*   ei = (const int*)d_in[1];
    const float* W1 = (const float*)d_in[2];
    const float* b1 = (const float*)d_in[3];
    const float* W2 = (const float*)d_in[4];
    const float* b2 = (const float*)d_in[5];
    const float* W3 = (const float*)d_in[6];
    const float* b3 = (const float*)d_in[7];
    const float* Wf = (const float*)d_in[8];
    const float* bf = (const float*)d_in[9];
    const float* Wd = (const float*)d_in[10];

    const int Nn = in_sizes[0] / 256;   // 10000
    const int E  = in_sizes[1] / 2;     // 320000
    const int* src = ei;
    const int* dst = ei + E;

    // workspace layout (~42.5 MB total)
    char* p = (char*)d_ws;
    auto alloc = [&](size_t bytes) -> char* {
        char* r = p;
        p += (bytes + 255) & ~(size_t)255;
        return r;
    };
    int*   counts   = (int*)alloc((size_t)Nn * 4);
    int*   cursor   = (int*)alloc((size_t)Nn * 4);
    int*   rowstart = (int*)alloc((size_t)(Nn + 1) * 4);
    float* dis      = (float*)alloc((size_t)Nn * 4);
    float* nrm      = (float*)alloc((size_t)E * 4);
    int*   csr_src  = (int*)alloc((size_t)E * 4);
    float* csr_w    = (float*)alloc((size_t)E * 4);
    float* bufA     = (float*)alloc((size_t)Nn * 256 * 4);
    float* bufB     = (float*)alloc((size_t)Nn * 256 * 4);
    float* out1     = (float*)alloc((size_t)Nn * 128 * 4);
    float* out2     = (float*)alloc((size_t)Nn * 128 * 4);
    float* out3     = (float*)alloc((size_t)Nn * 64 * 4);
    float* zz       = (float*)alloc((size_t)Nn * 64 * 4);
    float* zw       = (float*)alloc((size_t)Nn * 64 * 4);

    hipMemsetAsync(counts, 0, (size_t)Nn * 4, stream);
    hipMemsetAsync(cursor, 0, (size_t)Nn * 4, stream);

    int eb = (E + 255) / 256;
    int nb = (Nn + 255) / 256;
    count_kernel<<<eb, 256, 0, stream>>>(dst, counts, E);
    dis_kernel<<<nb, 256, 0, stream>>>(counts, dis, Nn);
    norm_kernel<<<eb, 256, 0, stream>>>(src, dst, dis, nrm, E);
    scan_kernel<<<1, 1024, 0, stream>>>(counts, rowstart, Nn);
    csr_fill_kernel<<<eb, 256, 0, stream>>>(src, dst, nrm, rowstart, cursor,
                                            csr_src, csr_w, E);

    int mb = (Nn + 63) / 64;  // 157
    dim3 g2(2, mb), g1(1, mb);

    // ---- TAGConv layer 1: 256 -> 128 ----
    gemm_kernel<false, false, false><<<g2, 256, 0, stream>>>(x,    W1 + 0 * 256 * 128, nullptr, out1, Nn, 128, 256);
    agg_kernel<<<Nn, 256, 0, stream>>>(x,    rowstart, csr_src, csr_w, bufA, 256);
    gemm_kernel<true,  false, false><<<g2, 256, 0, stream>>>(bufA, W1 + 1 * 256 * 128, nullptr, out1, Nn, 128, 256);
    agg_kernel<<<Nn, 256, 0, stream>>>(bufA, rowstart, csr_src, csr_w, bufB, 256);
    gemm_kernel<true,  false, false><<<g2, 256, 0, stream>>>(bufB, W1 + 2 * 256 * 128, nullptr, out1, Nn, 128, 256);
    agg_kernel<<<Nn, 256, 0, stream>>>(bufB, rowstart, csr_src, csr_w, bufA, 256);
    gemm_kernel<true,  true,  true ><<<g2, 256, 0, stream>>>(bufA, W1 + 3 * 256 * 128, b1,      out1, Nn, 128, 256);

    // ---- TAGConv layer 2: 128 -> 128 ----
    gemm_kernel<false, false, false><<<g2, 256, 0, stream>>>(out1, W2 + 0 * 128 * 128, nullptr, out2, Nn, 128, 128);
    agg_kernel<<<Nn, 128, 0, stream>>>(out1, rowstart, csr_src, csr_w, bufA, 128);
    gemm_kernel<true,  false, false><<<g2, 256, 0, stream>>>(bufA, W2 + 1 * 128 * 128, nullptr, out2, Nn, 128, 128);
    agg_kernel<<<Nn, 128, 0, stream>>>(bufA, rowstart, csr_src, csr_w, bufB, 128);
    gemm_kernel<true,  false, false><<<g2, 256, 0, stream>>>(bufB, W2 + 2 * 128 * 128, nullptr, out2, Nn, 128, 128);
    agg_kernel<<<Nn, 128, 0, stream>>>(bufB, rowstart, csr_src, csr_w, bufA, 128);
    gemm_kernel<true,  true,  true ><<<g2, 256, 0, stream>>>(bufA, W2 + 3 * 128 * 128, b2,      out2, Nn, 128, 128);

    // ---- TAGConv layer 3: 128 -> 64 ----
    gemm_kernel<false, false, false><<<g1, 256, 0, stream>>>(out2, W3 + 0 * 128 * 64, nullptr, out3, Nn, 64, 128);
    agg_kernel<<<Nn, 128, 0, stream>>>(out2, rowstart, csr_src, csr_w, bufA, 128);
    gemm_kernel<true,  false, false><<<g1, 256, 0, stream>>>(bufA, W3 + 1 * 128 * 64, nullptr, out3, Nn, 64, 128);
    agg_kernel<<<Nn, 128, 0, stream>>>(bufA, rowstart, csr_src, csr_w, bufB, 128);
    gemm_kernel<true,  false, false><<<g1, 256, 0, stream>>>(bufB, W3 + 2 * 128 * 64, nullptr, out3, Nn, 64, 128);
    agg_kernel<<<Nn, 128, 0, stream>>>(bufB, rowstart, csr_src, csr_w, bufA, 128);
    gemm_kernel<true,  true,  true ><<<g1, 256, 0, stream>>>(bufA, W3 + 3 * 128 * 64, b3,      out3, Nn, 64, 128);

    // ---- z = h @ Wf + bf ; zw = z @ Wd ----
    gemm_kernel<false, true,  false><<<g1, 256, 0, stream>>>(out3, Wf, bf,      zz, Nn, 64, 64);
    gemm_kernel<false, false, false><<<g1, 256, 0, stream>>>(zz,   Wd, nullptr, zw, Nn, 64, 64);

    // ---- adj = zw @ z^T ----
    decode_kernel<<<dim3(mb, mb), 256, 0, stream>>>(zw, zz, (float*)d_out, Nn);
}

// Round 2
// 754.888 us; speedup vs baseline: 3.7963x; 3.7963x over previous
//
#include <hip/hip_runtime.h>
#include <hip/hip_bf16.h>
#include <cstdint>
#include <cstddef>

// ---------------------------------------------------------------------------
// GraphAutoEncoder: 3x TAGConv(K=3) + linear + bilinear decode.
// N=10000 nodes, E=320000 edges, D: 256 -> 128 -> 128 -> 64.
// Round 1: decode via bf16 MFMA (16x16x32), LDS-free fragment loads.
// ---------------------------------------------------------------------------

typedef __attribute__((ext_vector_type(8))) short short8;   // 8 bf16 = 4 VGPR
typedef __attribute__((ext_vector_type(4))) float f32x4;

__global__ void count_kernel(const int* __restrict__ dst, int* __restrict__ counts, int E) {
    int e = blockIdx.x * blockDim.x + threadIdx.x;
    if (e < E) atomicAdd(&counts[dst[e]], 1);
}

__global__ void dis_kernel(const int* __restrict__ counts, float* __restrict__ dis, int n) {
    int i = blockIdx.x * blockDim.x + threadIdx.x;
    if (i < n) {
        int c = counts[i];
        dis[i] = (c > 0) ? rsqrtf((float)c) : 0.f;
    }
}

__global__ void norm_kernel(const int* __restrict__ src, const int* __restrict__ dst,
                            const float* __restrict__ dis, float* __restrict__ nrm, int E) {
    int e = blockIdx.x * blockDim.x + threadIdx.x;
    if (e < E) nrm[e] = dis[src[e]] * dis[dst[e]];
}

// single-block exclusive scan over counts[n] -> rowstart[n+1]
__global__ void scan_kernel(const int* __restrict__ counts, int* __restrict__ rowstart, int n) {
    __shared__ int sums[1024];
    int t = threadIdx.x;
    int chunk = (n + 1023) / 1024;
    int base = t * chunk;
    int s = 0;
    for (int i = 0; i < chunk; ++i) {
        int idx = base + i;
        if (idx < n) s += counts[idx];
    }
    sums[t] = s;
    __syncthreads();
    for (int off = 1; off < 1024; off <<= 1) {
        int v = (t >= off) ? sums[t - off] : 0;
        __syncthreads();
        sums[t] += v;
        __syncthreads();
    }
    int run = sums[t] - s;   // exclusive prefix of this thread's chunk
    for (int i = 0; i < chunk; ++i) {
        int idx = base + i;
        if (idx < n) { rowstart[idx] = run; run += counts[idx]; }
    }
    if (t == 1023) rowstart[n] = sums[1023];
}

__global__ void csr_fill_kernel(const int* __restrict__ src, const int* __restrict__ dst,
                                const float* __restrict__ nrm, const int* __restrict__ rowstart,
                                int* __restrict__ cursor, int* __restrict__ csr_src,
                                float* __restrict__ csr_w, int E) {
    int e = blockIdx.x * blockDim.x + threadIdx.x;
    if (e < E) {
        int d = dst[e];
        int pos = rowstart[d] + atomicAdd(&cursor[d], 1);
        csr_src[pos] = src[e];
        csr_w[pos]   = nrm[e];
    }
}

// out[n][t] = sum_{edges e with dst=n} w_e * h[src_e][t]; blockDim.x == D
__global__ void agg_kernel(const float* __restrict__ h, const int* __restrict__ rowstart,
                           const int* __restrict__ csr_src, const float* __restrict__ csr_w,
                           float* __restrict__ out, int D) {
    int n = blockIdx.x;
    int t = threadIdx.x;
    int beg = rowstart[n], end = rowstart[n + 1];
    float acc = 0.f;
    for (int j = beg; j < end; ++j) {
        acc += csr_w[j] * h[(size_t)csr_src[j] * D + t];
    }
    out[(size_t)n * D + t] = acc;
}

// fp32 -> bf16 (RNE), stored as ushort
__global__ void tobf16_kernel(const float* __restrict__ in, ushort* __restrict__ out, int n) {
    int i = blockIdx.x * blockDim.x + threadIdx.x;
    if (i < n) {
        __hip_bfloat16 h = __float2bfloat16(in[i]);
        out[i] = *reinterpret_cast<const ushort*>(&h);
    }
}

// C[M,Nc] (+)= A[M,K] @ B[K,Nc]; 64x64 tile, BK=32, 4x4 micro-tile.
template <bool ACCUM, bool BIAS, bool RELU>
__global__ __launch_bounds__(256) void gemm_kernel(
        const float* __restrict__ A, const float* __restrict__ B,
        const float* __restrict__ bias, float* __restrict__ C,
        int M, int Nc, int K) {
    __shared__ float As[32][68];  // As[k][m]
    __shared__ float Bs[32][68];  // Bs[k][n]
    int bm0 = blockIdx.y * 64;
    int bn0 = blockIdx.x * 64;
    int tid = threadIdx.x;
    int ty = tid / 16, tx = tid % 16;
    float acc[4][4] = {};

    for (int kk0 = 0; kk0 < K; kk0 += 32) {
        {
            int r  = tid / 4;             // 0..63
            int k0 = (tid % 4) * 8;       // 0..24
            bool va = (bm0 + r) < M;
            const float* pa = A + (size_t)(bm0 + r) * K + kk0 + k0;
            #pragma unroll
            for (int k = 0; k < 8; ++k) As[k0 + k][r] = va ? pa[k] : 0.f;

            int kb = tid / 8;             // 0..31
            int c0 = (tid % 8) * 8;       // 0..56
            const float* pb = B + (size_t)(kk0 + kb) * Nc + bn0 + c0;
            #pragma unroll
            for (int c = 0; c < 8; ++c) Bs[kb][c0 + c] = pb[c];
        }
        __syncthreads();
        #pragma unroll
        for (int k = 0; k < 32; ++k) {
            float4 a = *(const float4*)&As[k][ty * 4];
            float4 b = *(const float4*)&Bs[k][tx * 4];
            acc[0][0] += a.x * b.x; acc[0][1] += a.x * b.y; acc[0][2] += a.x * b.z; acc[0][3] += a.x * b.w;
            acc[1][0] += a.y * b.x; acc[1][1] += a.y * b.y; acc[1][2] += a.y * b.z; acc[1][3] += a.y * b.w;
            acc[2][0] += a.z * b.x; acc[2][1] += a.z * b.y; acc[2][2] += a.z * b.z; acc[2][3] += a.z * b.w;
            acc[3][0] += a.w * b.x; acc[3][1] += a.w * b.y; acc[3][2] += a.w * b.z; acc[3][3] += a.w * b.w;
        }
        __syncthreads();
    }

    int row0 = bm0 + ty * 4;
    int col0 = bn0 + tx * 4;
    #pragma unroll
    for (int i = 0; i < 4; ++i) {
        int row = row0 + i;
        if (row < M) {
            float* cp = &C[(size_t)row * Nc + col0];
            float v0 = acc[i][0], v1 = acc[i][1], v2 = acc[i][2], v3 = acc[i][3];
            if (ACCUM) {
                float4 c = *(const float4*)cp;
                v0 += c.x; v1 += c.y; v2 += c.z; v3 += c.w;
            }
            if (BIAS) {
                v0 += bias[col0 + 0]; v1 += bias[col0 + 1];
                v2 += bias[col0 + 2]; v3 += bias[col0 + 3];
            }
            if (RELU) {
                v0 = fmaxf(v0, 0.f); v1 = fmaxf(v1, 0.f);
                v2 = fmaxf(v2, 0.f); v3 = fmaxf(v3, 0.f);
            }
            float4 v = make_float4(v0, v1, v2, v3);
            *(float4*)cp = v;
        }
    }
}

// adj = ZW @ Z^T via bf16 MFMA. Block = 256 thr = 4 waves (2x2), tile 128x128,
// wave tile 64x64 = 4x4 fragments of 16x16, K=64 = 2 chained mfma.
// A-frag: row = lane&15, k = (lane>>4)*8 + j  (8 consecutive bf16 = 16B load)
// B-frag: col = lane&15, k = (lane>>4)*8 + j  (same: rows of Z)
// C/D   : col = lane&15, row = (lane>>4)*4 + reg   [m89-verified]
__global__ __launch_bounds__(256) void decode_mfma_kernel(
        const ushort* __restrict__ ZW, const ushort* __restrict__ Z,
        float* __restrict__ out, int Nn) {
    int tid  = threadIdx.x;
    int wave = tid >> 6, lane = tid & 63;
    int wr = wave >> 1, wc = wave & 1;
    int row0 = blockIdx.y * 128 + wr * 64;
    int col0 = blockIdx.x * 128 + wc * 64;
    int lr = lane & 15, lk = lane >> 4;

    short8 a[4][2], b[4][2];
    #pragma unroll
    for (int i = 0; i < 4; ++i) {
        int ra = min(row0 + i * 16 + lr, Nn - 1);
        int rb = min(col0 + i * 16 + lr, Nn - 1);
        const ushort* pa = ZW + (size_t)ra * 64 + lk * 8;
        const ushort* pb = Z  + (size_t)rb * 64 + lk * 8;
        a[i][0] = *(const short8*)pa;
        a[i][1] = *(const short8*)(pa + 32);
        b[i][0] = *(const short8*)pb;
        b[i][1] = *(const short8*)(pb + 32);
    }

    f32x4 acc[4][4];
    #pragma unroll
    for (int i = 0; i < 4; ++i)
        #pragma unroll
        for (int j = 0; j < 4; ++j)
            acc[i][j] = (f32x4){0.f, 0.f, 0.f, 0.f};

    #pragma unroll
    for (int i = 0; i < 4; ++i)
        #pragma unroll
        for (int j = 0; j < 4; ++j) {
            acc[i][j] = __builtin_amdgcn_mfma_f32_16x16x32_bf16(a[i][0], b[j][0], acc[i][j], 0, 0, 0);
            acc[i][j] = __builtin_amdgcn_mfma_f32_16x16x32_bf16(a[i][1], b[j][1], acc[i][j], 0, 0, 0);
        }

    bool full = (row0 + 64 <= Nn) && (col0 + 64 <= Nn);
    if (full) {
        #pragma unroll
        for (int mi = 0; mi < 4; ++mi) {
            int rbase = row0 + mi * 16 + lk * 4;
            #pragma unroll
            for (int ni = 0; ni < 4; ++ni) {
                int col = col0 + ni * 16 + lr;
                float* cp = out + (size_t)rbase * Nn + col;
                #pragma unroll
                for (int r = 0; r < 4; ++r)
                    cp[(size_t)r * Nn] = acc[mi][ni][r];
            }
        }
    } else {
        #pragma unroll
        for (int mi = 0; mi < 4; ++mi) {
            int rbase = row0 + mi * 16 + lk * 4;
            #pragma unroll
            for (int ni = 0; ni < 4; ++ni) {
                int col = col0 + ni * 16 + lr;
                if (col < Nn) {
                    #pragma unroll
                    for (int r = 0; r < 4; ++r) {
                        int row = rbase + r;
                        if (row < Nn)
                            out[(size_t)row * Nn + col] = acc[mi][ni][r];
                    }
                }
            }
        }
    }
}

extern "C" void kernel_launch(void* const* d_in, const int* in_sizes, int n_in,
                              void* d_out, int out_size, void* d_ws, size_t ws_size,
                              hipStream_t stream) {
    const float* x  = (const float*)d_in[0];
    const int*   ei = (const int*)d_in[1];
    const float* W1 = (const float*)d_in[2];
    const float* b1 = (const float*)d_in[3];
    const float* W2 = (const float*)d_in[4];
    const float* b2 = (const float*)d_in[5];
    const float* W3 = (const float*)d_in[6];
    const float* b3 = (const float*)d_in[7];
    const float* Wf = (const float*)d_in[8];
    const float* bf = (const float*)d_in[9];
    const float* Wd = (const float*)d_in[10];

    const int Nn = in_sizes[0] / 256;   // 10000
    const int E  = in_sizes[1] / 2;     // 320000
    const int* src = ei;
    const int* dst = ei + E;

    char* p = (char*)d_ws;
    auto alloc = [&](size_t bytes) -> char* {
        char* r = p;
        p += (bytes + 255) & ~(size_t)255;
        return r;
    };
    int*    counts   = (int*)alloc((size_t)Nn * 4);
    int*    cursor   = (int*)alloc((size_t)Nn * 4);
    int*    rowstart = (int*)alloc((size_t)(Nn + 1) * 4);
    float*  dis      = (float*)alloc((size_t)Nn * 4);
    float*  nrm      = (float*)alloc((size_t)E * 4);
    int*    csr_src  = (int*)alloc((size_t)E * 4);
    float*  csr_w    = (float*)alloc((size_t)E * 4);
    float*  bufA     = (float*)alloc((size_t)Nn * 256 * 4);
    float*  bufB     = (float*)alloc((size_t)Nn * 256 * 4);
    float*  out1     = (float*)alloc((size_t)Nn * 128 * 4);
    float*  out2     = (float*)alloc((size_t)Nn * 128 * 4);
    float*  out3     = (float*)alloc((size_t)Nn * 64 * 4);
    float*  zz       = (float*)alloc((size_t)Nn * 64 * 4);
    float*  zw       = (float*)alloc((size_t)Nn * 64 * 4);
    ushort* zzb      = (ushort*)alloc((size_t)Nn * 64 * 2);
    ushort* zwb      = (ushort*)alloc((size_t)Nn * 64 * 2);

    hipMemsetAsync(counts, 0, (size_t)Nn * 4, stream);
    hipMemsetAsync(cursor, 0, (size_t)Nn * 4, stream);

    int eb = (E + 255) / 256;
    int nb = (Nn + 255) / 256;
    count_kernel<<<eb, 256, 0, stream>>>(dst, counts, E);
    dis_kernel<<<nb, 256, 0, stream>>>(counts, dis, Nn);
    norm_kernel<<<eb, 256, 0, stream>>>(src, dst, dis, nrm, E);
    scan_kernel<<<1, 1024, 0, stream>>>(counts, rowstart, Nn);
    csr_fill_kernel<<<eb, 256, 0, stream>>>(src, dst, nrm, rowstart, cursor,
                                            csr_src, csr_w, E);

    int mb = (Nn + 63) / 64;  // 157
    dim3 g2(2, mb), g1(1, mb);

    // ---- TAGConv layer 1: 256 -> 128 ----
    gemm_kernel<false, false, false><<<g2, 256, 0, stream>>>(x,    W1 + 0 * 256 * 128, nullptr, out1, Nn, 128, 256);
    agg_kernel<<<Nn, 256, 0, stream>>>(x,    rowstart, csr_src, csr_w, bufA, 256);
    gemm_kernel<true,  false, false><<<g2, 256, 0, stream>>>(bufA, W1 + 1 * 256 * 128, nullptr, out1, Nn, 128, 256);
    agg_kernel<<<Nn, 256, 0, stream>>>(bufA, rowstart, csr_src, csr_w, bufB, 256);
    gemm_kernel<true,  false, false><<<g2, 256, 0, stream>>>(bufB, W1 + 2 * 256 * 128, nullptr, out1, Nn, 128, 256);
    agg_kernel<<<Nn, 256, 0, stream>>>(bufB, rowstart, csr_src, csr_w, bufA, 256);
    gemm_kernel<true,  true,  true ><<<g2, 256, 0, stream>>>(bufA, W1 + 3 * 256 * 128, b1,      out1, Nn, 128, 256);

    // ---- TAGConv layer 2: 128 -> 128 ----
    gemm_kernel<false, false, false><<<g2, 256, 0, stream>>>(out1, W2 + 0 * 128 * 128, nullptr, out2, Nn, 128, 128);
    agg_kernel<<<Nn, 128, 0, stream>>>(out1, rowstart, csr_src, csr_w, bufA, 128);
    gemm_kernel<true,  false, false><<<g2, 256, 0, stream>>>(bufA, W2 + 1 * 128 * 128, nullptr, out2, Nn, 128, 128);
    agg_kernel<<<Nn, 128, 0, stream>>>(bufA, rowstart, csr_src, csr_w, bufB, 128);
    gemm_kernel<true,  false, false><<<g2, 256, 0, stream>>>(bufB, W2 + 2 * 128 * 128, nullptr, out2, Nn, 128, 128);
    agg_kernel<<<Nn, 128, 0, stream>>>(bufB, rowstart, csr_src, csr_w, bufA, 128);
    gemm_kernel<true,  true,  true ><<<g2, 256, 0, stream>>>(bufA, W2 + 3 * 128 * 128, b2,      out2, Nn, 128, 128);

    // ---- TAGConv layer 3: 128 -> 64 ----
    gemm_kernel<false, false, false><<<g1, 256, 0, stream>>>(out2, W3 + 0 * 128 * 64, nullptr, out3, Nn, 64, 128);
    agg_kernel<<<Nn, 128, 0, stream>>>(out2, rowstart, csr_src, csr_w, bufA, 128);
    gemm_kernel<true,  false, false><<<g1, 256, 0, stream>>>(bufA, W3 + 1 * 128 * 64, nullptr, out3, Nn, 64, 128);
    agg_kernel<<<Nn, 128, 0, stream>>>(bufA, rowstart, csr_src, csr_w, bufB, 128);
    gemm_kernel<true,  false, false><<<g1, 256, 0, stream>>>(bufB, W3 + 2 * 128 * 64, nullptr, out3, Nn, 64, 128);
    agg_kernel<<<Nn, 128, 0, stream>>>(bufB, rowstart, csr_src, csr_w, bufA, 128);
    gemm_kernel<true,  true,  true ><<<g1, 256, 0, stream>>>(bufA, W3 + 3 * 128 * 64, b3,      out3, Nn, 64, 128);

    // ---- z = h @ Wf + bf ; zw = z @ Wd ----
    gemm_kernel<false, true,  false><<<g1, 256, 0, stream>>>(out3, Wf, bf,      zz, Nn, 64, 64);
    gemm_kernel<false, false, false><<<g1, 256, 0, stream>>>(zz,   Wd, nullptr, zw, Nn, 64, 64);

    // ---- convert z, zw to bf16 ----
    int cb = (Nn * 64 + 255) / 256;
    tobf16_kernel<<<cb, 256, 0, stream>>>(zz, zzb, Nn * 64);
    tobf16_kernel<<<cb, 256, 0, stream>>>(zw, zwb, Nn * 64);

    // ---- adj = zw @ z^T (bf16 MFMA) ----
    int db = (Nn + 127) / 128;  // 79
    decode_mfma_kernel<<<dim3(db, db), 256, 0, stream>>>(zwb, zzb, (float*)d_out, Nn);
}

// Round 3
// 534.696 us; speedup vs baseline: 5.3597x; 1.4118x over previous
//
#include <hip/hip_runtime.h>
#include <hip/hip_bf16.h>
#include <cstdint>
#include <cstddef>

// ---------------------------------------------------------------------------
// GraphAutoEncoder: 3x TAGConv(K=3) + linear + bilinear decode.
// N=10000 nodes, E=320000 edges, D: 256 -> 128 -> 128 -> 64.
// Round 2: TAGConv layers via stacked bf16 MFMA GEMM ([x|Ax|A2x|A3x] @ Wstack),
//          wave-per-node aggregation with batched edge broadcast.
// ---------------------------------------------------------------------------

typedef __attribute__((ext_vector_type(8))) short short8;   // 8 bf16 = 4 VGPR
typedef __attribute__((ext_vector_type(4))) float f32x4;

static __device__ __forceinline__ ushort f2bf(float f) {
    __hip_bfloat16 h = __float2bfloat16(f);
    return *reinterpret_cast<const ushort*>(&h);
}

__global__ void count_kernel(const int* __restrict__ dst, int* __restrict__ counts, int E) {
    int e = blockIdx.x * blockDim.x + threadIdx.x;
    if (e < E) atomicAdd(&counts[dst[e]], 1);
}

__global__ void dis_kernel(const int* __restrict__ counts, float* __restrict__ dis, int n) {
    int i = blockIdx.x * blockDim.x + threadIdx.x;
    if (i < n) {
        int c = counts[i];
        dis[i] = (c > 0) ? rsqrtf((float)c) : 0.f;
    }
}

__global__ void norm_kernel(const int* __restrict__ src, const int* __restrict__ dst,
                            const float* __restrict__ dis, float* __restrict__ nrm, int E) {
    int e = blockIdx.x * blockDim.x + threadIdx.x;
    if (e < E) nrm[e] = dis[src[e]] * dis[dst[e]];
}

// single-block exclusive scan over counts[n] -> rowstart[n+1]
__global__ void scan_kernel(const int* __restrict__ counts, int* __restrict__ rowstart, int n) {
    __shared__ int sums[1024];
    int t = threadIdx.x;
    int chunk = (n + 1023) / 1024;
    int base = t * chunk;
    int s = 0;
    for (int i = 0; i < chunk; ++i) {
        int idx = base + i;
        if (idx < n) s += counts[idx];
    }
    sums[t] = s;
    __syncthreads();
    for (int off = 1; off < 1024; off <<= 1) {
        int v = (t >= off) ? sums[t - off] : 0;
        __syncthreads();
        sums[t] += v;
        __syncthreads();
    }
    int run = sums[t] - s;
    for (int i = 0; i < chunk; ++i) {
        int idx = base + i;
        if (idx < n) { rowstart[idx] = run; run += counts[idx]; }
    }
    if (t == 1023) rowstart[n] = sums[1023];
}

__global__ void csr_fill_kernel(const int* __restrict__ src, const int* __restrict__ dst,
                                const float* __restrict__ nrm, const int* __restrict__ rowstart,
                                int* __restrict__ cursor, int* __restrict__ csr_src,
                                float* __restrict__ csr_w, int E) {
    int e = blockIdx.x * blockDim.x + threadIdx.x;
    if (e < E) {
        int d = dst[e];
        int pos = rowstart[d] + atomicAdd(&cursor[d], 1);
        csr_src[pos] = src[e];
        csr_w[pos]   = nrm[e];
    }
}

// fp32 -> bf16 (RNE)
__global__ void tobf16_kernel(const float* __restrict__ in, ushort* __restrict__ out, int n) {
    int i = blockIdx.x * blockDim.x + threadIdx.x;
    if (i < n) out[i] = f2bf(in[i]);
}

// W[4][DIN][DOUT] (hop-major) -> Wt[DOUT][4*DIN] bf16, k = hp*DIN + d
__global__ void prep_w_kernel(const float* __restrict__ W, ushort* __restrict__ Wt,
                              int DIN, int DOUT) {
    int i = blockIdx.x * blockDim.x + threadIdx.x;
    int tot = 4 * DIN * DOUT;
    if (i < tot) {
        int hp  = i / (DIN * DOUT);
        int rem = i - hp * DIN * DOUT;
        int d   = rem / DOUT;
        int o   = rem - d * DOUT;
        Wt[(size_t)o * (4 * DIN) + hp * DIN + d] = f2bf(W[i]);
    }
}

// wave-per-node aggregation: out[n] = sum_j w_j * h[src_j]; dual store f32+bf16.
// D=256 -> float4/lane, D=128 -> float2/lane. 4 nodes per 256-thread block.
template <int D>
__global__ __launch_bounds__(256) void agg2_kernel(
        const float* __restrict__ h, const int* __restrict__ rowstart,
        const int* __restrict__ csr_src, const float* __restrict__ csr_w,
        float* __restrict__ outF, ushort* __restrict__ outB, int Nn) {
    constexpr int VEC = D / 64;
    int wave = threadIdx.x >> 6, lane = threadIdx.x & 63;
    int n = blockIdx.x * 4 + wave;
    if (n >= Nn) return;
    int beg = rowstart[n], end = rowstart[n + 1];
    float acc[VEC];
    #pragma unroll
    for (int v = 0; v < VEC; ++v) acc[v] = 0.f;

    for (int j0 = beg; j0 < end; j0 += 64) {
        int take = end - j0;
        if (take > 64) take = 64;
        int s = 0; float w = 0.f;
        if (lane < take) { s = csr_src[j0 + lane]; w = csr_w[j0 + lane]; }
        for (int i = 0; i < take; ++i) {
            int   si = __shfl(s, i);
            float wi = __shfl(w, i);
            const float* hp = h + (size_t)si * D + lane * VEC;
            #pragma unroll
            for (int v = 0; v < VEC; ++v) acc[v] = fmaf(wi, hp[v], acc[v]);
        }
    }
    float*  of = outF + (size_t)n * D + lane * VEC;
    ushort* ob = outB + (size_t)n * D + lane * VEC;
    #pragma unroll
    for (int v = 0; v < VEC; ++v) {
        of[v] = acc[v];
        ob[v] = f2bf(acc[v]);
    }
}

// out[M,DOUT] = [A0|A1|A2|A3] @ Wt^T + bias (ReLU), A* = [M][DIN] bf16,
// Wt = [DOUT][4*DIN] bf16. Block: 256 thr, 32 rows; wave w covers cols
// w*(DOUT/4). Dual store f32 + bf16.
template <int DIN, int DOUT, bool RELU>
__global__ __launch_bounds__(256) void tag_gemm_kernel(
        const ushort* __restrict__ A0, const ushort* __restrict__ A1,
        const ushort* __restrict__ A2, const ushort* __restrict__ A3,
        const ushort* __restrict__ Wt, const float* __restrict__ bias,
        float* __restrict__ outF, ushort* __restrict__ outB, int M) {
    constexpr int CW = DOUT / 4;      // cols per wave
    constexpr int NJ = CW / 16;       // col fragments per wave
    constexpr int K4 = 4 * DIN;
    int tid = threadIdx.x, wave = tid >> 6, lane = tid & 63;
    int lr = lane & 15, lk = lane >> 4;
    int r0 = blockIdx.x * 32;
    int c0 = wave * CW;
    int ra0 = min(r0 + lr, M - 1);
    int ra1 = min(r0 + 16 + lr, M - 1);

    f32x4 acc[2][NJ];
    #pragma unroll
    for (int mi = 0; mi < 2; ++mi)
        #pragma unroll
        for (int nj = 0; nj < NJ; ++nj)
            acc[mi][nj] = (f32x4){0.f, 0.f, 0.f, 0.f};

    const ushort* As[4] = {A0, A1, A2, A3};
    #pragma unroll
    for (int hp = 0; hp < 4; ++hp) {
        const ushort* a0p = As[hp] + (size_t)ra0 * DIN + lk * 8;
        const ushort* a1p = As[hp] + (size_t)ra1 * DIN + lk * 8;
        #pragma unroll
        for (int kc = 0; kc < DIN; kc += 32) {
            short8 a0 = *(const short8*)(a0p + kc);
            short8 a1 = *(const short8*)(a1p + kc);
            #pragma unroll
            for (int nj = 0; nj < NJ; ++nj) {
                short8 b = *(const short8*)(Wt + (size_t)(c0 + nj * 16 + lr) * K4
                                            + hp * DIN + kc + lk * 8);
                acc[0][nj] = __builtin_amdgcn_mfma_f32_16x16x32_bf16(a0, b, acc[0][nj], 0, 0, 0);
                acc[1][nj] = __builtin_amdgcn_mfma_f32_16x16x32_bf16(a1, b, acc[1][nj], 0, 0, 0);
            }
        }
    }

    #pragma unroll
    for (int nj = 0; nj < NJ; ++nj) {
        int c = c0 + nj * 16 + lr;
        float bv = bias[c];
        #pragma unroll
        for (int mi = 0; mi < 2; ++mi) {
            int rbase = r0 + mi * 16 + lk * 4;
            #pragma unroll
            for (int r = 0; r < 4; ++r) {
                int row = rbase + r;
                if (row < M) {
                    float v = acc[mi][nj][r] + bv;
                    if (RELU) v = fmaxf(v, 0.f);
                    outF[(size_t)row * DOUT + c] = v;
                    outB[(size_t)row * DOUT + c] = f2bf(v);
                }
            }
        }
    }
}

// C[M,Nc] (+)= A[M,K] @ B[K,Nc]; fp32, 64x64 tile (used for small Wf/Wd GEMMs)
template <bool ACCUM, bool BIAS, bool RELU>
__global__ __launch_bounds__(256) void gemm_kernel(
        const float* __restrict__ A, const float* __restrict__ B,
        const float* __restrict__ bias, float* __restrict__ C,
        int M, int Nc, int K) {
    __shared__ float As[32][68];
    __shared__ float Bs[32][68];
    int bm0 = blockIdx.y * 64;
    int bn0 = blockIdx.x * 64;
    int tid = threadIdx.x;
    int ty = tid / 16, tx = tid % 16;
    float acc[4][4] = {};

    for (int kk0 = 0; kk0 < K; kk0 += 32) {
        {
            int r  = tid / 4;
            int k0 = (tid % 4) * 8;
            bool va = (bm0 + r) < M;
            const float* pa = A + (size_t)(bm0 + r) * K + kk0 + k0;
            #pragma unroll
            for (int k = 0; k < 8; ++k) As[k0 + k][r] = va ? pa[k] : 0.f;

            int kb = tid / 8;
            int c0 = (tid % 8) * 8;
            const float* pb = B + (size_t)(kk0 + kb) * Nc + bn0 + c0;
            #pragma unroll
            for (int c = 0; c < 8; ++c) Bs[kb][c0 + c] = pb[c];
        }
        __syncthreads();
        #pragma unroll
        for (int k = 0; k < 32; ++k) {
            float4 a = *(const float4*)&As[k][ty * 4];
            float4 b = *(const float4*)&Bs[k][tx * 4];
            acc[0][0] += a.x * b.x; acc[0][1] += a.x * b.y; acc[0][2] += a.x * b.z; acc[0][3] += a.x * b.w;
            acc[1][0] += a.y * b.x; acc[1][1] += a.y * b.y; acc[1][2] += a.y * b.z; acc[1][3] += a.y * b.w;
            acc[2][0] += a.z * b.x; acc[2][1] += a.z * b.y; acc[2][2] += a.z * b.z; acc[2][3] += a.z * b.w;
            acc[3][0] += a.w * b.x; acc[3][1] += a.w * b.y; acc[3][2] += a.w * b.z; acc[3][3] += a.w * b.w;
        }
        __syncthreads();
    }

    int row0 = bm0 + ty * 4;
    int col0 = bn0 + tx * 4;
    #pragma unroll
    for (int i = 0; i < 4; ++i) {
        int row = row0 + i;
        if (row < M) {
            float* cp = &C[(size_t)row * Nc + col0];
            float v0 = acc[i][0], v1 = acc[i][1], v2 = acc[i][2], v3 = acc[i][3];
            if (ACCUM) {
                float4 c = *(const float4*)cp;
                v0 += c.x; v1 += c.y; v2 += c.z; v3 += c.w;
            }
            if (BIAS) {
                v0 += bias[col0 + 0]; v1 += bias[col0 + 1];
                v2 += bias[col0 + 2]; v3 += bias[col0 + 3];
            }
            if (RELU) {
                v0 = fmaxf(v0, 0.f); v1 = fmaxf(v1, 0.f);
                v2 = fmaxf(v2, 0.f); v3 = fmaxf(v3, 0.f);
            }
            float4 v = make_float4(v0, v1, v2, v3);
            *(float4*)cp = v;
        }
    }
}

// adj = ZW @ Z^T via bf16 MFMA. Block 256 thr = 4 waves (2x2), tile 128x128.
__global__ __launch_bounds__(256) void decode_mfma_kernel(
        const ushort* __restrict__ ZW, const ushort* __restrict__ Z,
        float* __restrict__ out, int Nn) {
    int tid  = threadIdx.x;
    int wave = tid >> 6, lane = tid & 63;
    int wr = wave >> 1, wc = wave & 1;
    int row0 = blockIdx.y * 128 + wr * 64;
    int col0 = blockIdx.x * 128 + wc * 64;
    int lr = lane & 15, lk = lane >> 4;

    short8 a[4][2], b[4][2];
    #pragma unroll
    for (int i = 0; i < 4; ++i) {
        int ra = min(row0 + i * 16 + lr, Nn - 1);
        int rb = min(col0 + i * 16 + lr, Nn - 1);
        const ushort* pa = ZW + (size_t)ra * 64 + lk * 8;
        const ushort* pb = Z  + (size_t)rb * 64 + lk * 8;
        a[i][0] = *(const short8*)pa;
        a[i][1] = *(const short8*)(pa + 32);
        b[i][0] = *(const short8*)pb;
        b[i][1] = *(const short8*)(pb + 32);
    }

    f32x4 acc[4][4];
    #pragma unroll
    for (int i = 0; i < 4; ++i)
        #pragma unroll
        for (int j = 0; j < 4; ++j)
            acc[i][j] = (f32x4){0.f, 0.f, 0.f, 0.f};

    #pragma unroll
    for (int i = 0; i < 4; ++i)
        #pragma unroll
        for (int j = 0; j < 4; ++j) {
            acc[i][j] = __builtin_amdgcn_mfma_f32_16x16x32_bf16(a[i][0], b[j][0], acc[i][j], 0, 0, 0);
            acc[i][j] = __builtin_amdgcn_mfma_f32_16x16x32_bf16(a[i][1], b[j][1], acc[i][j], 0, 0, 0);
        }

    bool full = (row0 + 64 <= Nn) && (col0 + 64 <= Nn);
    if (full) {
        #pragma unroll
        for (int mi = 0; mi < 4; ++mi) {
            int rbase = row0 + mi * 16 + lk * 4;
            #pragma unroll
            for (int ni = 0; ni < 4; ++ni) {
                int col = col0 + ni * 16 + lr;
                float* cp = out + (size_t)rbase * Nn + col;
                #pragma unroll
                for (int r = 0; r < 4; ++r)
                    cp[(size_t)r * Nn] = acc[mi][ni][r];
            }
        }
    } else {
        #pragma unroll
        for (int mi = 0; mi < 4; ++mi) {
            int rbase = row0 + mi * 16 + lk * 4;
            #pragma unroll
            for (int ni = 0; ni < 4; ++ni) {
                int col = col0 + ni * 16 + lr;
                if (col < Nn) {
                    #pragma unroll
                    for (int r = 0; r < 4; ++r) {
                        int row = rbase + r;
                        if (row < Nn)
                            out[(size_t)row * Nn + col] = acc[mi][ni][r];
                    }
                }
            }
        }
    }
}

extern "C" void kernel_launch(void* const* d_in, const int* in_sizes, int n_in,
                              void* d_out, int out_size, void* d_ws, size_t ws_size,
                              hipStream_t stream) {
    const float* x  = (const float*)d_in[0];
    const int*   ei = (const int*)d_in[1];
    const float* W1 = (const float*)d_in[2];
    const float* b1 = (const float*)d_in[3];
    const float* W2 = (const float*)d_in[4];
    const float* b2 = (const float*)d_in[5];
    const float* W3 = (const float*)d_in[6];
    const float* b3 = (const float*)d_in[7];
    const float* Wf = (const float*)d_in[8];
    const float* bf = (const float*)d_in[9];
    const float* Wd = (const float*)d_in[10];

    const int Nn = in_sizes[0] / 256;   // 10000
    const int E  = in_sizes[1] / 2;     // 320000
    const int* src = ei;
    const int* dst = ei + E;

    char* p = (char*)d_ws;
    auto alloc = [&](size_t bytes) -> char* {
        char* r = p;
        p += (bytes + 255) & ~(size_t)255;
        return r;
    };
    int*    counts   = (int*)alloc((size_t)Nn * 4);
    int*    cursor   = (int*)alloc((size_t)Nn * 4);
    int*    rowstart = (int*)alloc((size_t)(Nn + 1) * 4);
    float*  dis      = (float*)alloc((size_t)Nn * 4);
    float*  nrm      = (float*)alloc((size_t)E * 4);
    int*    csr_src  = (int*)alloc((size_t)E * 4);
    float*  csr_w    = (float*)alloc((size_t)E * 4);
    float*  bufA     = (float*)alloc((size_t)Nn * 256 * 4);   // f32 hop chain
    float*  bufB     = (float*)alloc((size_t)Nn * 256 * 4);
    float*  bufC     = (float*)alloc((size_t)Nn * 256 * 4);
    ushort* xb       = (ushort*)alloc((size_t)Nn * 256 * 2);  // bf16 hop0 (layer1)
    ushort* h1b      = (ushort*)alloc((size_t)Nn * 256 * 2);  // bf16 hops
    ushort* h2b      = (ushort*)alloc((size_t)Nn * 256 * 2);
    ushort* h3b      = (ushort*)alloc((size_t)Nn * 256 * 2);
    float*  out1f    = (float*)alloc((size_t)Nn * 128 * 4);
    ushort* out1b    = (ushort*)alloc((size_t)Nn * 128 * 2);
    float*  out2f    = (float*)alloc((size_t)Nn * 128 * 4);
    ushort* out2b    = (ushort*)alloc((size_t)Nn * 128 * 2);
    float*  out3f    = (float*)alloc((size_t)Nn * 64 * 4);
    ushort* out3b    = (ushort*)alloc((size_t)Nn * 64 * 2);
    float*  zz       = (float*)alloc((size_t)Nn * 64 * 4);
    float*  zw       = (float*)alloc((size_t)Nn * 64 * 4);
    ushort* zzb      = (ushort*)alloc((size_t)Nn * 64 * 2);
    ushort* zwb      = (ushort*)alloc((size_t)Nn * 64 * 2);
    ushort* Wt1      = (ushort*)alloc((size_t)128 * 1024 * 2);
    ushort* Wt2      = (ushort*)alloc((size_t)128 * 512 * 2);
    ushort* Wt3      = (ushort*)alloc((size_t)64 * 512 * 2);

    hipMemsetAsync(counts, 0, (size_t)Nn * 4, stream);
    hipMemsetAsync(cursor, 0, (size_t)Nn * 4, stream);

    int eb = (E + 255) / 256;
    int nb = (Nn + 255) / 256;
    count_kernel<<<eb, 256, 0, stream>>>(dst, counts, E);
    dis_kernel<<<nb, 256, 0, stream>>>(counts, dis, Nn);
    norm_kernel<<<eb, 256, 0, stream>>>(src, dst, dis, nrm, E);
    scan_kernel<<<1, 1024, 0, stream>>>(counts, rowstart, Nn);
    csr_fill_kernel<<<eb, 256, 0, stream>>>(src, dst, nrm, rowstart, cursor,
                                            csr_src, csr_w, E);

    // weight prep + x -> bf16
    prep_w_kernel<<<(4 * 256 * 128 + 255) / 256, 256, 0, stream>>>(W1, Wt1, 256, 128);
    prep_w_kernel<<<(4 * 128 * 128 + 255) / 256, 256, 0, stream>>>(W2, Wt2, 128, 128);
    prep_w_kernel<<<(4 * 128 * 64 + 255) / 256, 256, 0, stream>>>(W3, Wt3, 128, 64);
    tobf16_kernel<<<(Nn * 256 + 255) / 256, 256, 0, stream>>>(x, xb, Nn * 256);

    int ab = (Nn + 3) / 4;              // agg blocks (4 nodes/block)
    int gb = (Nn + 31) / 32;            // tag_gemm blocks (32 rows/block)

    // ---- layer 1: 256 -> 128 ----
    agg2_kernel<256><<<ab, 256, 0, stream>>>(x,    rowstart, csr_src, csr_w, bufA, h1b, Nn);
    agg2_kernel<256><<<ab, 256, 0, stream>>>(bufA, rowstart, csr_src, csr_w, bufB, h2b, Nn);
    agg2_kernel<256><<<ab, 256, 0, stream>>>(bufB, rowstart, csr_src, csr_w, bufC, h3b, Nn);
    tag_gemm_kernel<256, 128, true><<<gb, 256, 0, stream>>>(xb, h1b, h2b, h3b, Wt1, b1,
                                                            out1f, out1b, Nn);

    // ---- layer 2: 128 -> 128 ----
    agg2_kernel<128><<<ab, 256, 0, stream>>>(out1f, rowstart, csr_src, csr_w, bufA, h1b, Nn);
    agg2_kernel<128><<<ab, 256, 0, stream>>>(bufA,  rowstart, csr_src, csr_w, bufB, h2b, Nn);
    agg2_kernel<128><<<ab, 256, 0, stream>>>(bufB,  rowstart, csr_src, csr_w, bufC, h3b, Nn);
    tag_gemm_kernel<128, 128, true><<<gb, 256, 0, stream>>>(out1b, h1b, h2b, h3b, Wt2, b2,
                                                            out2f, out2b, Nn);

    // ---- layer 3: 128 -> 64 ----
    agg2_kernel<128><<<ab, 256, 0, stream>>>(out2f, rowstart, csr_src, csr_w, bufA, h1b, Nn);
    agg2_kernel<128><<<ab, 256, 0, stream>>>(bufA,  rowstart, csr_src, csr_w, bufB, h2b, Nn);
    agg2_kernel<128><<<ab, 256, 0, stream>>>(bufB,  rowstart, csr_src, csr_w, bufC, h3b, Nn);
    tag_gemm_kernel<128, 64, true><<<gb, 256, 0, stream>>>(out2b, h1b, h2b, h3b, Wt3, b3,
                                                           out3f, out3b, Nn);

    // ---- z = h @ Wf + bf ; zw = z @ Wd (fp32, small) ----
    int mb = (Nn + 63) / 64;
    dim3 g1(1, mb);
    gemm_kernel<false, true,  false><<<g1, 256, 0, stream>>>(out3f, Wf, bf,      zz, Nn, 64, 64);
    gemm_kernel<false, false, false><<<g1, 256, 0, stream>>>(zz,    Wd, nullptr, zw, Nn, 64, 64);

    int cb = (Nn * 64 + 255) / 256;
    tobf16_kernel<<<cb, 256, 0, stream>>>(zz, zzb, Nn * 64);
    tobf16_kernel<<<cb, 256, 0, stream>>>(zw, zwb, Nn * 64);

    // ---- adj = zw @ z^T (bf16 MFMA) ----
    int db = (Nn + 127) / 128;
    decode_mfma_kernel<<<dim3(db, db), 256, 0, stream>>>(zwb, zzb, (float*)d_out, Nn);
}

// Round 4
// 431.064 us; speedup vs baseline: 6.6482x; 1.2404x over previous
//
#include <hip/hip_runtime.h>
#include <hip/hip_bf16.h>
#include <cstdint>
#include <cstddef>

// ---------------------------------------------------------------------------
// GraphAutoEncoder: 3x TAGConv(K=3) + linear + bilinear decode.
// N=10000, E=320000, D: 256 -> 128 -> 128 -> 64.
// Round 3: bf16 everywhere. agg reads/writes bf16 (L2-resident table, 2 edges
// per iter at D=128); decode via 32x32x16 MFMA (128B-coalesced stores);
// final projections via bf16 MFMA lin64 kernels.
// ---------------------------------------------------------------------------

typedef __attribute__((ext_vector_type(8)))  short short8;   // 8 bf16
typedef __attribute__((ext_vector_type(4)))  float f32x4;
typedef __attribute__((ext_vector_type(16))) float f32x16;

static __device__ __forceinline__ ushort f2bf(float f) {
    __hip_bfloat16 h = __float2bfloat16(f);
    return *reinterpret_cast<const ushort*>(&h);
}
static __device__ __forceinline__ float bf2f(ushort u) {
    union { uint i; float f; } v; v.i = ((uint)u) << 16; return v.f;
}

// ---------------- graph setup ----------------

__global__ void count_kernel(const int* __restrict__ dst, int* __restrict__ counts, int E) {
    int e = blockIdx.x * blockDim.x + threadIdx.x;
    if (e < E) atomicAdd(&counts[dst[e]], 1);
}

__global__ void dis_kernel(const int* __restrict__ counts, float* __restrict__ dis, int n) {
    int i = blockIdx.x * blockDim.x + threadIdx.x;
    if (i < n) {
        int c = counts[i];
        dis[i] = (c > 0) ? rsqrtf((float)c) : 0.f;
    }
}

__global__ void norm_kernel(const int* __restrict__ src, const int* __restrict__ dst,
                            const float* __restrict__ dis, float* __restrict__ nrm, int E) {
    int e = blockIdx.x * blockDim.x + threadIdx.x;
    if (e < E) nrm[e] = dis[src[e]] * dis[dst[e]];
}

__global__ void scan_kernel(const int* __restrict__ counts, int* __restrict__ rowstart, int n) {
    __shared__ int sums[1024];
    int t = threadIdx.x;
    int chunk = (n + 1023) / 1024;
    int base = t * chunk;
    int s = 0;
    for (int i = 0; i < chunk; ++i) {
        int idx = base + i;
        if (idx < n) s += counts[idx];
    }
    sums[t] = s;
    __syncthreads();
    for (int off = 1; off < 1024; off <<= 1) {
        int v = (t >= off) ? sums[t - off] : 0;
        __syncthreads();
        sums[t] += v;
        __syncthreads();
    }
    int run = sums[t] - s;
    for (int i = 0; i < chunk; ++i) {
        int idx = base + i;
        if (idx < n) { rowstart[idx] = run; run += counts[idx]; }
    }
    if (t == 1023) rowstart[n] = sums[1023];
}

__global__ void csr_fill_kernel(const int* __restrict__ src, const int* __restrict__ dst,
                                const float* __restrict__ nrm, const int* __restrict__ rowstart,
                                int* __restrict__ cursor, int* __restrict__ csr_src,
                                float* __restrict__ csr_w, int E) {
    int e = blockIdx.x * blockDim.x + threadIdx.x;
    if (e < E) {
        int d = dst[e];
        int pos = rowstart[d] + atomicAdd(&cursor[d], 1);
        csr_src[pos] = src[e];
        csr_w[pos]   = nrm[e];
    }
}

// ---------------- conversions / weight prep ----------------

__global__ void tobf16_kernel(const float* __restrict__ in, ushort* __restrict__ out, int n) {
    int i = blockIdx.x * blockDim.x + threadIdx.x;
    if (i < n) out[i] = f2bf(in[i]);
}

// W[4][DIN][DOUT] -> Wt[DOUT][4*DIN] bf16, k = hp*DIN + d
__global__ void prep_w_kernel(const float* __restrict__ W, ushort* __restrict__ Wt,
                              int DIN, int DOUT) {
    int i = blockIdx.x * blockDim.x + threadIdx.x;
    int tot = 4 * DIN * DOUT;
    if (i < tot) {
        int hp  = i / (DIN * DOUT);
        int rem = i - hp * DIN * DOUT;
        int d   = rem / DOUT;
        int o   = rem - d * DOUT;
        Wt[(size_t)o * (4 * DIN) + hp * DIN + d] = f2bf(W[i]);
    }
}

// W[K][C] -> Wt[C][K] bf16
__global__ void prep_wt_kernel(const float* __restrict__ W, ushort* __restrict__ Wt,
                               int K, int C) {
    int i = blockIdx.x * blockDim.x + threadIdx.x;
    if (i < K * C) {
        int k = i / C, c = i - k * C;
        Wt[(size_t)c * K + k] = f2bf(W[i]);
    }
}

// ---------------- aggregation (bf16 in, bf16 out, fp32 accum) ----------------
// wave-per-node; D=256: 1 edge/iter (64 lanes x 4 elems), D=128: 2 edges/iter
// (32-lane half-waves), xor-reduce at end.
template <int D>
__global__ __launch_bounds__(256) void agg3_kernel(
        const ushort* __restrict__ h, const int* __restrict__ rowstart,
        const int* __restrict__ csr_src, const float* __restrict__ csr_w,
        ushort* __restrict__ out, int Nn) {
    constexpr int LPE = D / 4;        // lanes per edge
    constexpr int EPI = 64 / LPE;     // edges per iteration (1 or 2)
    int wave = threadIdx.x >> 6, lane = threadIdx.x & 63;
    int n = blockIdx.x * 4 + wave;
    if (n >= Nn) return;
    int sub = lane / LPE;
    int ll  = lane % LPE;
    int beg = rowstart[n], end = rowstart[n + 1];

    float a0 = 0.f, a1 = 0.f, a2 = 0.f, a3 = 0.f;
    for (int j0 = beg; j0 < end; j0 += 64) {
        int take = end - j0;
        if (take > 64) take = 64;
        int s = 0; float w = 0.f;
        if (lane < take) { s = csr_src[j0 + lane]; w = csr_w[j0 + lane]; }
        for (int i = 0; i < take; i += EPI) {
            int e = i + sub;                 // lanes >= take carry w=0 -> no-op
            float wi = __shfl(w, e);
            int   si = __shfl(s, e);
            ushort4 hv = *(const ushort4*)(h + (size_t)si * D + ll * 4);
            a0 = fmaf(wi, bf2f(hv.x), a0);
            a1 = fmaf(wi, bf2f(hv.y), a1);
            a2 = fmaf(wi, bf2f(hv.z), a2);
            a3 = fmaf(wi, bf2f(hv.w), a3);
        }
    }
    if (EPI == 2) {
        a0 += __shfl_xor(a0, 32);
        a1 += __shfl_xor(a1, 32);
        a2 += __shfl_xor(a2, 32);
        a3 += __shfl_xor(a3, 32);
    }
    if (EPI == 1 || sub == 0) {
        ushort4 o;
        o.x = f2bf(a0); o.y = f2bf(a1); o.z = f2bf(a2); o.w = f2bf(a3);
        *(ushort4*)(out + (size_t)n * D + ll * 4) = o;
    }
}

// ---------------- TAGConv stacked GEMM ----------------
// out[M,DOUT] = relu([A0|A1|A2|A3] @ Wt^T + bias), bf16 in/out, fp32 acc.
template <int DIN, int DOUT>
__global__ __launch_bounds__(256) void tag_gemm_kernel(
        const ushort* __restrict__ A0, const ushort* __restrict__ A1,
        const ushort* __restrict__ A2, const ushort* __restrict__ A3,
        const ushort* __restrict__ Wt, const float* __restrict__ bias,
        ushort* __restrict__ outB, int M) {
    constexpr int CW = DOUT / 4;
    constexpr int NJ = CW / 16;
    constexpr int K4 = 4 * DIN;
    int tid = threadIdx.x, wave = tid >> 6, lane = tid & 63;
    int lr = lane & 15, lk = lane >> 4;
    int r0 = blockIdx.x * 32;
    int c0 = wave * CW;
    int ra0 = min(r0 + lr, M - 1);
    int ra1 = min(r0 + 16 + lr, M - 1);

    f32x4 acc[2][NJ];
    #pragma unroll
    for (int mi = 0; mi < 2; ++mi)
        #pragma unroll
        for (int nj = 0; nj < NJ; ++nj)
            acc[mi][nj] = (f32x4){0.f, 0.f, 0.f, 0.f};

    const ushort* As[4] = {A0, A1, A2, A3};
    #pragma unroll
    for (int hp = 0; hp < 4; ++hp) {
        const ushort* a0p = As[hp] + (size_t)ra0 * DIN + lk * 8;
        const ushort* a1p = As[hp] + (size_t)ra1 * DIN + lk * 8;
        #pragma unroll
        for (int kc = 0; kc < DIN; kc += 32) {
            short8 a0 = *(const short8*)(a0p + kc);
            short8 a1 = *(const short8*)(a1p + kc);
            #pragma unroll
            for (int nj = 0; nj < NJ; ++nj) {
                short8 b = *(const short8*)(Wt + (size_t)(c0 + nj * 16 + lr) * K4
                                            + hp * DIN + kc + lk * 8);
                acc[0][nj] = __builtin_amdgcn_mfma_f32_16x16x32_bf16(a0, b, acc[0][nj], 0, 0, 0);
                acc[1][nj] = __builtin_amdgcn_mfma_f32_16x16x32_bf16(a1, b, acc[1][nj], 0, 0, 0);
            }
        }
    }

    #pragma unroll
    for (int nj = 0; nj < NJ; ++nj) {
        int c = c0 + nj * 16 + lr;
        float bv = bias[c];
        #pragma unroll
        for (int mi = 0; mi < 2; ++mi) {
            int rbase = r0 + mi * 16 + lk * 4;
            #pragma unroll
            for (int r = 0; r < 4; ++r) {
                int row = rbase + r;
                if (row < M) {
                    float v = fmaxf(acc[mi][nj][r] + bv, 0.f);
                    outB[(size_t)row * DOUT + c] = f2bf(v);
                }
            }
        }
    }
}

// ---------------- small 64x64 projection: out = A @ Wt^T (+bias), bf16 ----
template <bool BIAS>
__global__ __launch_bounds__(256) void lin64_kernel(
        const ushort* __restrict__ A, const ushort* __restrict__ Wt,
        const float* __restrict__ bias, ushort* __restrict__ out, int M) {
    int tid = threadIdx.x, wave = tid >> 6, lane = tid & 63;
    int lr = lane & 15, lk = lane >> 4;
    int r0 = blockIdx.x * 128 + wave * 32;
    int ra0 = min(r0 + lr, M - 1);
    int ra1 = min(r0 + 16 + lr, M - 1);

    short8 a[2][2], b[4][2];
    #pragma unroll
    for (int kc = 0; kc < 2; ++kc) {
        a[0][kc] = *(const short8*)(A + (size_t)ra0 * 64 + kc * 32 + lk * 8);
        a[1][kc] = *(const short8*)(A + (size_t)ra1 * 64 + kc * 32 + lk * 8);
        #pragma unroll
        for (int nj = 0; nj < 4; ++nj)
            b[nj][kc] = *(const short8*)(Wt + (size_t)(nj * 16 + lr) * 64 + kc * 32 + lk * 8);
    }

    f32x4 acc[2][4];
    #pragma unroll
    for (int mi = 0; mi < 2; ++mi)
        #pragma unroll
        for (int nj = 0; nj < 4; ++nj) {
            acc[mi][nj] = (f32x4){0.f, 0.f, 0.f, 0.f};
            acc[mi][nj] = __builtin_amdgcn_mfma_f32_16x16x32_bf16(a[mi][0], b[nj][0], acc[mi][nj], 0, 0, 0);
            acc[mi][nj] = __builtin_amdgcn_mfma_f32_16x16x32_bf16(a[mi][1], b[nj][1], acc[mi][nj], 0, 0, 0);
        }

    #pragma unroll
    for (int nj = 0; nj < 4; ++nj) {
        int c = nj * 16 + lr;
        float bv = BIAS ? bias[c] : 0.f;
        #pragma unroll
        for (int mi = 0; mi < 2; ++mi) {
            int rbase = r0 + mi * 16 + lk * 4;
            #pragma unroll
            for (int r = 0; r < 4; ++r) {
                int row = rbase + r;
                if (row < M)
                    out[(size_t)row * 64 + c] = f2bf(acc[mi][nj][r] + bv);
            }
        }
    }
}

// ---------------- decode: adj = ZW @ Z^T via 32x32x16 MFMA ----------------
// Block 256 thr = 4 waves (2x2), tile 128x128; wave 64x64 = 2x2 frags of 32x32.
// A: row=lane&31, k=(lane>>5)*8+j ; B: col=lane&31, same k.
// C/D: col=lane&31, row=(reg&3)+8*(reg>>2)+4*(lane>>5)  [m74/m101]
__global__ __launch_bounds__(256) void decode32_kernel(
        const ushort* __restrict__ ZW, const ushort* __restrict__ Z,
        float* __restrict__ out, int Nn) {
    int tid = threadIdx.x, wave = tid >> 6, lane = tid & 63;
    int wr = wave >> 1, wc = wave & 1;
    int row0 = blockIdx.y * 128 + wr * 64;
    int col0 = blockIdx.x * 128 + wc * 64;
    int lr = lane & 31, hi = lane >> 5;

    short8 a[2][4], b[2][4];
    #pragma unroll
    for (int mi = 0; mi < 2; ++mi) {
        int ra = min(row0 + mi * 32 + lr, Nn - 1);
        int rb = min(col0 + mi * 32 + lr, Nn - 1);
        const ushort* pa = ZW + (size_t)ra * 64 + hi * 8;
        const ushort* pb = Z  + (size_t)rb * 64 + hi * 8;
        #pragma unroll
        for (int kc = 0; kc < 4; ++kc) {
            a[mi][kc] = *(const short8*)(pa + kc * 16);
            b[mi][kc] = *(const short8*)(pb + kc * 16);
        }
    }

    f32x16 acc[2][2];
    #pragma unroll
    for (int mi = 0; mi < 2; ++mi)
        #pragma unroll
        for (int nj = 0; nj < 2; ++nj) {
            f32x16 c;
            #pragma unroll
            for (int q = 0; q < 16; ++q) c[q] = 0.f;
            #pragma unroll
            for (int kc = 0; kc < 4; ++kc)
                c = __builtin_amdgcn_mfma_f32_32x32x16_bf16(a[mi][kc], b[nj][kc], c, 0, 0, 0);
            acc[mi][nj] = c;
        }

    bool full = (row0 + 64 <= Nn) && (col0 + 64 <= Nn);
    #pragma unroll
    for (int mi = 0; mi < 2; ++mi)
        #pragma unroll
        for (int nj = 0; nj < 2; ++nj) {
            int cb = col0 + nj * 32 + lr;
            #pragma unroll
            for (int reg = 0; reg < 16; ++reg) {
                int row = row0 + mi * 32 + (reg & 3) + 8 * (reg >> 2) + 4 * hi;
                if (full) {
                    out[(size_t)row * Nn + cb] = acc[mi][nj][reg];
                } else {
                    if (row < Nn && cb < Nn)
                        out[(size_t)row * Nn + cb] = acc[mi][nj][reg];
                }
            }
        }
}

// ---------------- launch ----------------

extern "C" void kernel_launch(void* const* d_in, const int* in_sizes, int n_in,
                              void* d_out, int out_size, void* d_ws, size_t ws_size,
                              hipStream_t stream) {
    const float* x  = (const float*)d_in[0];
    const int*   ei = (const int*)d_in[1];
    const float* W1 = (const float*)d_in[2];
    const float* b1 = (const float*)d_in[3];
    const float* W2 = (const float*)d_in[4];
    const float* b2 = (const float*)d_in[5];
    const float* W3 = (const float*)d_in[6];
    const float* b3 = (const float*)d_in[7];
    const float* Wf = (const float*)d_in[8];
    const float* bf = (const float*)d_in[9];
    const float* Wd = (const float*)d_in[10];

    const int Nn = in_sizes[0] / 256;   // 10000
    const int E  = in_sizes[1] / 2;     // 320000
    const int* src = ei;
    const int* dst = ei + E;

    char* p = (char*)d_ws;
    auto alloc = [&](size_t bytes) -> char* {
        char* r = p;
        p += (bytes + 255) & ~(size_t)255;
        return r;
    };
    int*    counts   = (int*)alloc((size_t)Nn * 4);
    int*    cursor   = (int*)alloc((size_t)Nn * 4);
    int*    rowstart = (int*)alloc((size_t)(Nn + 1) * 4);
    float*  dis      = (float*)alloc((size_t)Nn * 4);
    float*  nrm      = (float*)alloc((size_t)E * 4);
    int*    csr_src  = (int*)alloc((size_t)E * 4);
    float*  csr_w    = (float*)alloc((size_t)E * 4);
    ushort* xb       = (ushort*)alloc((size_t)Nn * 256 * 2);
    ushort* h1b      = (ushort*)alloc((size_t)Nn * 256 * 2);
    ushort* h2b      = (ushort*)alloc((size_t)Nn * 256 * 2);
    ushort* h3b      = (ushort*)alloc((size_t)Nn * 256 * 2);
    ushort* out1b    = (ushort*)alloc((size_t)Nn * 128 * 2);
    ushort* out2b    = (ushort*)alloc((size_t)Nn * 128 * 2);
    ushort* out3b    = (ushort*)alloc((size_t)Nn * 64 * 2);
    ushort* zzb      = (ushort*)alloc((size_t)Nn * 64 * 2);
    ushort* zwb      = (ushort*)alloc((size_t)Nn * 64 * 2);
    ushort* Wt1      = (ushort*)alloc((size_t)128 * 1024 * 2);
    ushort* Wt2      = (ushort*)alloc((size_t)128 * 512 * 2);
    ushort* Wt3      = (ushort*)alloc((size_t)64 * 512 * 2);
    ushort* Wfb      = (ushort*)alloc((size_t)64 * 64 * 2);
    ushort* Wdb      = (ushort*)alloc((size_t)64 * 64 * 2);

    hipMemsetAsync(counts, 0, (size_t)Nn * 4, stream);
    hipMemsetAsync(cursor, 0, (size_t)Nn * 4, stream);

    int eb = (E + 255) / 256;
    int nb = (Nn + 255) / 256;
    count_kernel<<<eb, 256, 0, stream>>>(dst, counts, E);
    dis_kernel<<<nb, 256, 0, stream>>>(counts, dis, Nn);
    norm_kernel<<<eb, 256, 0, stream>>>(src, dst, dis, nrm, E);
    scan_kernel<<<1, 1024, 0, stream>>>(counts, rowstart, Nn);
    csr_fill_kernel<<<eb, 256, 0, stream>>>(src, dst, nrm, rowstart, cursor,
                                            csr_src, csr_w, E);

    prep_w_kernel<<<(4 * 256 * 128 + 255) / 256, 256, 0, stream>>>(W1, Wt1, 256, 128);
    prep_w_kernel<<<(4 * 128 * 128 + 255) / 256, 256, 0, stream>>>(W2, Wt2, 128, 128);
    prep_w_kernel<<<(4 * 128 * 64 + 255) / 256, 256, 0, stream>>>(W3, Wt3, 128, 64);
    prep_wt_kernel<<<(64 * 64 + 255) / 256, 256, 0, stream>>>(Wf, Wfb, 64, 64);
    prep_wt_kernel<<<(64 * 64 + 255) / 256, 256, 0, stream>>>(Wd, Wdb, 64, 64);
    tobf16_kernel<<<(Nn * 256 + 255) / 256, 256, 0, stream>>>(x, xb, Nn * 256);

    int ab = (Nn + 3) / 4;
    int gb = (Nn + 31) / 32;

    // ---- layer 1: 256 -> 128 ----
    agg3_kernel<256><<<ab, 256, 0, stream>>>(xb,  rowstart, csr_src, csr_w, h1b, Nn);
    agg3_kernel<256><<<ab, 256, 0, stream>>>(h1b, rowstart, csr_src, csr_w, h2b, Nn);
    agg3_kernel<256><<<ab, 256, 0, stream>>>(h2b, rowstart, csr_src, csr_w, h3b, Nn);
    tag_gemm_kernel<256, 128><<<gb, 256, 0, stream>>>(xb, h1b, h2b, h3b, Wt1, b1, out1b, Nn);

    // ---- layer 2: 128 -> 128 ----
    agg3_kernel<128><<<ab, 256, 0, stream>>>(out1b, rowstart, csr_src, csr_w, h1b, Nn);
    agg3_kernel<128><<<ab, 256, 0, stream>>>(h1b,   rowstart, csr_src, csr_w, h2b, Nn);
    agg3_kernel<128><<<ab, 256, 0, stream>>>(h2b,   rowstart, csr_src, csr_w, h3b, Nn);
    tag_gemm_kernel<128, 128><<<gb, 256, 0, stream>>>(out1b, h1b, h2b, h3b, Wt2, b2, out2b, Nn);

    // ---- layer 3: 128 -> 64 ----
    agg3_kernel<128><<<ab, 256, 0, stream>>>(out2b, rowstart, csr_src, csr_w, h1b, Nn);
    agg3_kernel<128><<<ab, 256, 0, stream>>>(h1b,   rowstart, csr_src, csr_w, h2b, Nn);
    agg3_kernel<128><<<ab, 256, 0, stream>>>(h2b,   rowstart, csr_src, csr_w, h3b, Nn);
    tag_gemm_kernel<128, 64><<<gb, 256, 0, stream>>>(out2b, h1b, h2b, h3b, Wt3, b3, out3b, Nn);

    // ---- z = h @ Wf + bf ; zw = z @ Wd ----
    int lb = (Nn + 127) / 128;
    lin64_kernel<true ><<<lb, 256, 0, stream>>>(out3b, Wfb, bf,      zzb, Nn);
    lin64_kernel<false><<<lb, 256, 0, stream>>>(zzb,   Wdb, nullptr, zwb, Nn);

    // ---- adj = zw @ z^T ----
    int db = (Nn + 127) / 128;
    decode32_kernel<<<dim3(db, db), 256, 0, stream>>>(zwb, zzb, (float*)d_out, Nn);
}

// Round 5
// 358.985 us; speedup vs baseline: 7.9831x; 1.2008x over previous
//
#include <hip/hip_runtime.h>
#include <hip/hip_bf16.h>
#include <cstdint>
#include <cstddef>

// ---------------------------------------------------------------------------
// GraphAutoEncoder: 3x TAGConv(K=3) + linear + bilinear decode.
// N=10000, E=320000, D: 256 -> 128 -> 128 -> 64.
// Round 4: short8 (16B/lane) aggregation (4 edges/iter @128, 2 @256);
// fused setup (scan+dis, csr_fill+norm, one prep kernel, fused dual
// projection via LDS); nontemporal decode stores. 19 graph dispatches.
// ---------------------------------------------------------------------------

typedef __attribute__((ext_vector_type(8)))  short short8;   // 8 bf16
typedef __attribute__((ext_vector_type(4)))  float f32x4;
typedef __attribute__((ext_vector_type(16))) float f32x16;

static __device__ __forceinline__ ushort f2bf(float f) {
    __hip_bfloat16 h = __float2bfloat16(f);
    return *reinterpret_cast<const ushort*>(&h);
}
static __device__ __forceinline__ float bf2f(ushort u) {
    union { uint i; float f; } v; v.i = ((uint)u) << 16; return v.f;
}

// ---------------- graph setup ----------------

__global__ void count_kernel(const int* __restrict__ dst, int* __restrict__ counts, int E) {
    int e = blockIdx.x * blockDim.x + threadIdx.x;
    if (e < E) atomicAdd(&counts[dst[e]], 1);
}

// exclusive scan counts[n] -> rowstart[n+1], plus dis[i] = rsqrt(deg) fused
__global__ void scan_kernel(const int* __restrict__ counts, int* __restrict__ rowstart,
                            float* __restrict__ dis, int n) {
    __shared__ int sums[1024];
    int t = threadIdx.x;
    int chunk = (n + 1023) / 1024;
    int base = t * chunk;
    int s = 0;
    for (int i = 0; i < chunk; ++i) {
        int idx = base + i;
        if (idx < n) s += counts[idx];
    }
    sums[t] = s;
    __syncthreads();
    for (int off = 1; off < 1024; off <<= 1) {
        int v = (t >= off) ? sums[t - off] : 0;
        __syncthreads();
        sums[t] += v;
        __syncthreads();
    }
    int run = sums[t] - s;
    for (int i = 0; i < chunk; ++i) {
        int idx = base + i;
        if (idx < n) {
            rowstart[idx] = run;
            int c = counts[idx];
            dis[idx] = (c > 0) ? rsqrtf((float)c) : 0.f;
            run += c;
        }
    }
    if (t == 1023) rowstart[n] = sums[1023];
}

// CSR fill with gcn-norm weight computed inline: w = dis[src]*dis[dst]
__global__ void csr_fill_kernel(const int* __restrict__ src, const int* __restrict__ dst,
                                const float* __restrict__ dis, const int* __restrict__ rowstart,
                                int* __restrict__ cursor, int* __restrict__ csr_src,
                                float* __restrict__ csr_w, int E) {
    int e = blockIdx.x * blockDim.x + threadIdx.x;
    if (e < E) {
        int d = dst[e];
        int s = src[e];
        int pos = rowstart[d] + atomicAdd(&cursor[d], 1);
        csr_src[pos] = s;
        csr_w[pos]   = dis[s] * dis[d];
    }
}

// ---------------- fused conversions / weight prep ----------------
// region 0: x (Nn*256) f32->bf16
// region 1-3: W[4][DIN][DOUT] -> Wt[DOUT][4*DIN]
// region 4-5: W[K][C] -> Wt[C][K]
static __device__ __forceinline__ void prep_w_elem(const float* W, ushort* Wt,
                                                   int DIN, int DOUT, int i) {
    int hp  = i / (DIN * DOUT);
    int rem = i - hp * DIN * DOUT;
    int d   = rem / DOUT;
    int o   = rem - d * DOUT;
    Wt[(size_t)o * (4 * DIN) + hp * DIN + d] = f2bf(W[i]);
}
static __device__ __forceinline__ void prep_wt_elem(const float* W, ushort* Wt,
                                                    int K, int C, int i) {
    int k = i / C, c = i - k * C;
    Wt[(size_t)c * K + k] = f2bf(W[i]);
}

__global__ void prep_all_kernel(const float* __restrict__ x, ushort* __restrict__ xb, int nx,
                                const float* __restrict__ W1, ushort* __restrict__ Wt1,
                                const float* __restrict__ W2, ushort* __restrict__ Wt2,
                                const float* __restrict__ W3, ushort* __restrict__ Wt3,
                                const float* __restrict__ Wf, ushort* __restrict__ Wfb,
                                const float* __restrict__ Wd, ushort* __restrict__ Wdb) {
    const int n1 = 4 * 256 * 128, n2 = 4 * 128 * 128, n3 = 4 * 128 * 64, nf = 64 * 64;
    int i = blockIdx.x * blockDim.x + threadIdx.x;
    if (i < nx) { xb[i] = f2bf(x[i]); return; }
    i -= nx;
    if (i < n1) { prep_w_elem(W1, Wt1, 256, 128, i); return; }
    i -= n1;
    if (i < n2) { prep_w_elem(W2, Wt2, 128, 128, i); return; }
    i -= n2;
    if (i < n3) { prep_w_elem(W3, Wt3, 128, 64, i); return; }
    i -= n3;
    if (i < nf) { prep_wt_elem(Wf, Wfb, 64, 64, i); return; }
    i -= nf;
    if (i < nf) { prep_wt_elem(Wd, Wdb, 64, 64, i); return; }
}

// ---------------- aggregation (bf16 in/out, fp32 accum, short8 loads) -------
// wave-per-node. LPE = D/8 lanes per edge (16B/lane), EPI = 64/LPE edges/iter.
template <int D>
__global__ __launch_bounds__(256) void agg4_kernel(
        const ushort* __restrict__ h, const int* __restrict__ rowstart,
        const int* __restrict__ csr_src, const float* __restrict__ csr_w,
        ushort* __restrict__ out, int Nn) {
    constexpr int LPE = D / 8;        // 32 (D=256) or 16 (D=128)
    constexpr int EPI = 64 / LPE;     // 2 or 4
    int wave = threadIdx.x >> 6, lane = threadIdx.x & 63;
    int n = blockIdx.x * 4 + wave;
    if (n >= Nn) return;
    int sub = lane / LPE;
    int ll  = lane % LPE;
    int beg = rowstart[n], end = rowstart[n + 1];

    float acc[8];
    #pragma unroll
    for (int v = 0; v < 8; ++v) acc[v] = 0.f;

    for (int j0 = beg; j0 < end; j0 += 64) {
        int take = end - j0;
        if (take > 64) take = 64;
        int s = 0; float w = 0.f;
        if (lane < take) { s = csr_src[j0 + lane]; w = csr_w[j0 + lane]; }
        for (int i = 0; i < take; i += EPI) {
            int e = i + sub;                 // e >= take lanes carry w=0
            float wi = __shfl(w, e);
            int   si = __shfl(s, e);
            short8 hv = *(const short8*)(h + (size_t)si * D + ll * 8);
            #pragma unroll
            for (int v = 0; v < 8; ++v)
                acc[v] = fmaf(wi, bf2f((ushort)hv[v]), acc[v]);
        }
    }
    if (EPI == 4) {
        #pragma unroll
        for (int v = 0; v < 8; ++v) acc[v] += __shfl_xor(acc[v], 16);
    }
    #pragma unroll
    for (int v = 0; v < 8; ++v) acc[v] += __shfl_xor(acc[v], 32);

    if (sub == 0) {
        short8 o;
        #pragma unroll
        for (int v = 0; v < 8; ++v) o[v] = (short)f2bf(acc[v]);
        *(short8*)(out + (size_t)n * D + ll * 8) = o;
    }
}

// ---------------- TAGConv stacked GEMM ----------------
template <int DIN, int DOUT>
__global__ __launch_bounds__(256) void tag_gemm_kernel(
        const ushort* __restrict__ A0, const ushort* __restrict__ A1,
        const ushort* __restrict__ A2, const ushort* __restrict__ A3,
        const ushort* __restrict__ Wt, const float* __restrict__ bias,
        ushort* __restrict__ outB, int M) {
    constexpr int CW = DOUT / 4;
    constexpr int NJ = CW / 16;
    constexpr int K4 = 4 * DIN;
    int tid = threadIdx.x, wave = tid >> 6, lane = tid & 63;
    int lr = lane & 15, lk = lane >> 4;
    int r0 = blockIdx.x * 32;
    int c0 = wave * CW;
    int ra0 = min(r0 + lr, M - 1);
    int ra1 = min(r0 + 16 + lr, M - 1);

    f32x4 acc[2][NJ];
    #pragma unroll
    for (int mi = 0; mi < 2; ++mi)
        #pragma unroll
        for (int nj = 0; nj < NJ; ++nj)
            acc[mi][nj] = (f32x4){0.f, 0.f, 0.f, 0.f};

    const ushort* As[4] = {A0, A1, A2, A3};
    #pragma unroll
    for (int hp = 0; hp < 4; ++hp) {
        const ushort* a0p = As[hp] + (size_t)ra0 * DIN + lk * 8;
        const ushort* a1p = As[hp] + (size_t)ra1 * DIN + lk * 8;
        #pragma unroll
        for (int kc = 0; kc < DIN; kc += 32) {
            short8 a0 = *(const short8*)(a0p + kc);
            short8 a1 = *(const short8*)(a1p + kc);
            #pragma unroll
            for (int nj = 0; nj < NJ; ++nj) {
                short8 b = *(const short8*)(Wt + (size_t)(c0 + nj * 16 + lr) * K4
                                            + hp * DIN + kc + lk * 8);
                acc[0][nj] = __builtin_amdgcn_mfma_f32_16x16x32_bf16(a0, b, acc[0][nj], 0, 0, 0);
                acc[1][nj] = __builtin_amdgcn_mfma_f32_16x16x32_bf16(a1, b, acc[1][nj], 0, 0, 0);
            }
        }
    }

    #pragma unroll
    for (int nj = 0; nj < NJ; ++nj) {
        int c = c0 + nj * 16 + lr;
        float bv = bias[c];
        #pragma unroll
        for (int mi = 0; mi < 2; ++mi) {
            int rbase = r0 + mi * 16 + lk * 4;
            #pragma unroll
            for (int r = 0; r < 4; ++r) {
                int row = rbase + r;
                if (row < M) {
                    float v = fmaxf(acc[mi][nj][r] + bv, 0.f);
                    outB[(size_t)row * DOUT + c] = f2bf(v);
                }
            }
        }
    }
}

// ---------------- fused dual projection: zz = A@Wf^T+bf ; zw = zz@Wd^T ------
// Wave computes 32 rows; zz staged through padded LDS between the MFMA passes.
__global__ __launch_bounds__(256) void lin64_dual_kernel(
        const ushort* __restrict__ A, const ushort* __restrict__ Wfb,
        const float* __restrict__ bias, const ushort* __restrict__ Wdb,
        ushort* __restrict__ zz, ushort* __restrict__ zw, int M) {
    __shared__ ushort zl[4][32][72];   // +8 ushort pad: row stride 144B = 9x16B
    int tid = threadIdx.x, wave = tid >> 6, lane = tid & 63;
    int lr = lane & 15, lk = lane >> 4;
    int r0 = blockIdx.x * 128 + wave * 32;
    int ra0 = min(r0 + lr, M - 1);
    int ra1 = min(r0 + 16 + lr, M - 1);

    // pass 1: zz = A @ Wf^T + bf
    short8 a[2][2], b[4][2];
    #pragma unroll
    for (int kc = 0; kc < 2; ++kc) {
        a[0][kc] = *(const short8*)(A + (size_t)ra0 * 64 + kc * 32 + lk * 8);
        a[1][kc] = *(const short8*)(A + (size_t)ra1 * 64 + kc * 32 + lk * 8);
        #pragma unroll
        for (int nj = 0; nj < 4; ++nj)
            b[nj][kc] = *(const short8*)(Wfb + (size_t)(nj * 16 + lr) * 64 + kc * 32 + lk * 8);
    }
    f32x4 acc1[2][4];
    #pragma unroll
    for (int mi = 0; mi < 2; ++mi)
        #pragma unroll
        for (int nj = 0; nj < 4; ++nj) {
            acc1[mi][nj] = (f32x4){0.f, 0.f, 0.f, 0.f};
            acc1[mi][nj] = __builtin_amdgcn_mfma_f32_16x16x32_bf16(a[mi][0], b[nj][0], acc1[mi][nj], 0, 0, 0);
            acc1[mi][nj] = __builtin_amdgcn_mfma_f32_16x16x32_bf16(a[mi][1], b[nj][1], acc1[mi][nj], 0, 0, 0);
        }

    #pragma unroll
    for (int nj = 0; nj < 4; ++nj) {
        int c = nj * 16 + lr;
        float bv = bias[c];
        #pragma unroll
        for (int mi = 0; mi < 2; ++mi) {
            int rloc = mi * 16 + lk * 4;
            #pragma unroll
            for (int r = 0; r < 4; ++r) {
                ushort u = f2bf(acc1[mi][nj][r] + bv);
                zl[wave][rloc + r][c] = u;
                int row = r0 + rloc + r;
                if (row < M) zz[(size_t)row * 64 + c] = u;
            }
        }
    }
    __syncthreads();

    // pass 2: zw = zz @ Wd^T
    short8 a2[2][2], b2[4][2];
    #pragma unroll
    for (int kc = 0; kc < 2; ++kc) {
        a2[0][kc] = *(const short8*)&zl[wave][lr][kc * 32 + lk * 8];
        a2[1][kc] = *(const short8*)&zl[wave][16 + lr][kc * 32 + lk * 8];
        #pragma unroll
        for (int nj = 0; nj < 4; ++nj)
            b2[nj][kc] = *(const short8*)(Wdb + (size_t)(nj * 16 + lr) * 64 + kc * 32 + lk * 8);
    }
    f32x4 acc2[2][4];
    #pragma unroll
    for (int mi = 0; mi < 2; ++mi)
        #pragma unroll
        for (int nj = 0; nj < 4; ++nj) {
            acc2[mi][nj] = (f32x4){0.f, 0.f, 0.f, 0.f};
            acc2[mi][nj] = __builtin_amdgcn_mfma_f32_16x16x32_bf16(a2[mi][0], b2[nj][0], acc2[mi][nj], 0, 0, 0);
            acc2[mi][nj] = __builtin_amdgcn_mfma_f32_16x16x32_bf16(a2[mi][1], b2[nj][1], acc2[mi][nj], 0, 0, 0);
        }
    #pragma unroll
    for (int nj = 0; nj < 4; ++nj) {
        int c = nj * 16 + lr;
        #pragma unroll
        for (int mi = 0; mi < 2; ++mi) {
            int rbase = r0 + mi * 16 + lk * 4;
            #pragma unroll
            for (int r = 0; r < 4; ++r) {
                int row = rbase + r;
                if (row < M) zw[(size_t)row * 64 + c] = f2bf(acc2[mi][nj][r]);
            }
        }
    }
}

// ---------------- decode: adj = ZW @ Z^T via 32x32x16 MFMA ----------------
__global__ __launch_bounds__(256) void decode32_kernel(
        const ushort* __restrict__ ZW, const ushort* __restrict__ Z,
        float* __restrict__ out, int Nn) {
    int tid = threadIdx.x, wave = tid >> 6, lane = tid & 63;
    int wr = wave >> 1, wc = wave & 1;
    int row0 = blockIdx.y * 128 + wr * 64;
    int col0 = blockIdx.x * 128 + wc * 64;
    int lr = lane & 31, hi = lane >> 5;

    short8 a[2][4], b[2][4];
    #pragma unroll
    for (int mi = 0; mi < 2; ++mi) {
        int ra = min(row0 + mi * 32 + lr, Nn - 1);
        int rb = min(col0 + mi * 32 + lr, Nn - 1);
        const ushort* pa = ZW + (size_t)ra * 64 + hi * 8;
        const ushort* pb = Z  + (size_t)rb * 64 + hi * 8;
        #pragma unroll
        for (int kc = 0; kc < 4; ++kc) {
            a[mi][kc] = *(const short8*)(pa + kc * 16);
            b[mi][kc] = *(const short8*)(pb + kc * 16);
        }
    }

    f32x16 acc[2][2];
    #pragma unroll
    for (int mi = 0; mi < 2; ++mi)
        #pragma unroll
        for (int nj = 0; nj < 2; ++nj) {
            f32x16 c;
            #pragma unroll
            for (int q = 0; q < 16; ++q) c[q] = 0.f;
            #pragma unroll
            for (int kc = 0; kc < 4; ++kc)
                c = __builtin_amdgcn_mfma_f32_32x32x16_bf16(a[mi][kc], b[nj][kc], c, 0, 0, 0);
            acc[mi][nj] = c;
        }

    bool full = (row0 + 64 <= Nn) && (col0 + 64 <= Nn);
    #pragma unroll
    for (int mi = 0; mi < 2; ++mi)
        #pragma unroll
        for (int nj = 0; nj < 2; ++nj) {
            int cb = col0 + nj * 32 + lr;
            #pragma unroll
            for (int reg = 0; reg < 16; ++reg) {
                int row = row0 + mi * 32 + (reg & 3) + 8 * (reg >> 2) + 4 * hi;
                if (full) {
                    __builtin_nontemporal_store(acc[mi][nj][reg], &out[(size_t)row * Nn + cb]);
                } else {
                    if (row < Nn && cb < Nn)
                        __builtin_nontemporal_store(acc[mi][nj][reg], &out[(size_t)row * Nn + cb]);
                }
            }
        }
}

// ---------------- launch ----------------

extern "C" void kernel_launch(void* const* d_in, const int* in_sizes, int n_in,
                              void* d_out, int out_size, void* d_ws, size_t ws_size,
                              hipStream_t stream) {
    const float* x  = (const float*)d_in[0];
    const int*   ei = (const int*)d_in[1];
    const float* W1 = (const float*)d_in[2];
    const float* b1 = (const float*)d_in[3];
    const float* W2 = (const float*)d_in[4];
    const float* b2 = (const float*)d_in[5];
    const float* W3 = (const float*)d_in[6];
    const float* b3 = (const float*)d_in[7];
    const float* Wf = (const float*)d_in[8];
    const float* bf = (const float*)d_in[9];
    const float* Wd = (const float*)d_in[10];

    const int Nn = in_sizes[0] / 256;   // 10000
    const int E  = in_sizes[1] / 2;     // 320000
    const int* src = ei;
    const int* dst = ei + E;

    char* p = (char*)d_ws;
    auto alloc = [&](size_t bytes) -> char* {
        char* r = p;
        p += (bytes + 255) & ~(size_t)255;
        return r;
    };
    size_t nslot = ((size_t)Nn * 4 + 255) & ~(size_t)255;
    int*    counts   = (int*)alloc((size_t)Nn * 4);
    int*    cursor   = (int*)alloc((size_t)Nn * 4);
    int*    rowstart = (int*)alloc((size_t)(Nn + 1) * 4);
    float*  dis      = (float*)alloc((size_t)Nn * 4);
    int*    csr_src  = (int*)alloc((size_t)E * 4);
    float*  csr_w    = (float*)alloc((size_t)E * 4);
    ushort* xb       = (ushort*)alloc((size_t)Nn * 256 * 2);
    ushort* h1b      = (ushort*)alloc((size_t)Nn * 256 * 2);
    ushort* h2b      = (ushort*)alloc((size_t)Nn * 256 * 2);
    ushort* h3b      = (ushort*)alloc((size_t)Nn * 256 * 2);
    ushort* out1b    = (ushort*)alloc((size_t)Nn * 128 * 2);
    ushort* out2b    = (ushort*)alloc((size_t)Nn * 128 * 2);
    ushort* out3b    = (ushort*)alloc((size_t)Nn * 64 * 2);
    ushort* zzb      = (ushort*)alloc((size_t)Nn * 64 * 2);
    ushort* zwb      = (ushort*)alloc((size_t)Nn * 64 * 2);
    ushort* Wt1      = (ushort*)alloc((size_t)128 * 1024 * 2);
    ushort* Wt2      = (ushort*)alloc((size_t)128 * 512 * 2);
    ushort* Wt3      = (ushort*)alloc((size_t)64 * 512 * 2);
    ushort* Wfb      = (ushort*)alloc((size_t)64 * 64 * 2);
    ushort* Wdb      = (ushort*)alloc((size_t)64 * 64 * 2);

    // counts+cursor are adjacent slots: one memset covers both
    hipMemsetAsync(counts, 0, nslot + (size_t)Nn * 4, stream);

    int eb = (E + 255) / 256;
    count_kernel<<<eb, 256, 0, stream>>>(dst, counts, E);
    scan_kernel<<<1, 1024, 0, stream>>>(counts, rowstart, dis, Nn);
    csr_fill_kernel<<<eb, 256, 0, stream>>>(src, dst, dis, rowstart, cursor,
                                            csr_src, csr_w, E);

    int nx = Nn * 256;
    int nprep = nx + 4 * 256 * 128 + 4 * 128 * 128 + 4 * 128 * 64 + 64 * 64 + 64 * 64;
    prep_all_kernel<<<(nprep + 255) / 256, 256, 0, stream>>>(
        x, xb, nx, W1, Wt1, W2, Wt2, W3, Wt3, Wf, Wfb, Wd, Wdb);

    int ab = (Nn + 3) / 4;
    int gb = (Nn + 31) / 32;

    // ---- layer 1: 256 -> 128 ----
    agg4_kernel<256><<<ab, 256, 0, stream>>>(xb,  rowstart, csr_src, csr_w, h1b, Nn);
    agg4_kernel<256><<<ab, 256, 0, stream>>>(h1b, rowstart, csr_src, csr_w, h2b, Nn);
    agg4_kernel<256><<<ab, 256, 0, stream>>>(h2b, rowstart, csr_src, csr_w, h3b, Nn);
    tag_gemm_kernel<256, 128><<<gb, 256, 0, stream>>>(xb, h1b, h2b, h3b, Wt1, b1, out1b, Nn);

    // ---- layer 2: 128 -> 128 ----
    agg4_kernel<128><<<ab, 256, 0, stream>>>(out1b, rowstart, csr_src, csr_w, h1b, Nn);
    agg4_kernel<128><<<ab, 256, 0, stream>>>(h1b,   rowstart, csr_src, csr_w, h2b, Nn);
    agg4_kernel<128><<<ab, 256, 0, stream>>>(h2b,   rowstart, csr_src, csr_w, h3b, Nn);
    tag_gemm_kernel<128, 128><<<gb, 256, 0, stream>>>(out1b, h1b, h2b, h3b, Wt2, b2, out2b, Nn);

    // ---- layer 3: 128 -> 64 ----
    agg4_kernel<128><<<ab, 256, 0, stream>>>(out2b, rowstart, csr_src, csr_w, h1b, Nn);
    agg4_kernel<128><<<ab, 256, 0, stream>>>(h1b,   rowstart, csr_src, csr_w, h2b, Nn);
    agg4_kernel<128><<<ab, 256, 0, stream>>>(h2b,   rowstart, csr_src, csr_w, h3b, Nn);
    tag_gemm_kernel<128, 64><<<gb, 256, 0, stream>>>(out2b, h1b, h2b, h3b, Wt3, b3, out3b, Nn);

    // ---- zz = h @ Wf + bf ; zw = zz @ Wd (fused) ----
    int lb = (Nn + 127) / 128;
    lin64_dual_kernel<<<lb, 256, 0, stream>>>(out3b, Wfb, bf, Wdb, zzb, zwb, Nn);

    // ---- adj = zw @ z^T ----
    int db = (Nn + 127) / 128;
    decode32_kernel<<<dim3(db, db), 256, 0, stream>>>(zwb, zzb, (float*)d_out, Nn);
}

// Round 6
// 332.322 us; speedup vs baseline: 8.6236x; 1.0802x over previous
//
#include <hip/hip_runtime.h>
#include <hip/hip_bf16.h>
#include <cstdint>
#include <cstddef>

// ---------------------------------------------------------------------------
// GraphAutoEncoder: 3x TAGConv(K=3) + linear + bilinear decode.
// N=10000, E=320000, D: 256 -> 128 -> 128 -> 64.
// Round 5: Horner restructure. (A^k x) Wk = A^k (x Wk), so project first
// (proj_gemm: y_k = h @ W[k], bias folded into y0) then aggregate in the
// output space: out = relu(y0 + A(y1 + A(y2 + A y3))). Gather traffic drops
// 984 -> 615 MB; layer-3 hops run at D=64 (8 edges/iter).
// ---------------------------------------------------------------------------

typedef __attribute__((ext_vector_type(8)))  short short8;   // 8 bf16
typedef __attribute__((ext_vector_type(4)))  float f32x4;
typedef __attribute__((ext_vector_type(16))) float f32x16;

static __device__ __forceinline__ ushort f2bf(float f) {
    __hip_bfloat16 h = __float2bfloat16(f);
    return *reinterpret_cast<const ushort*>(&h);
}
static __device__ __forceinline__ float bf2f(ushort u) {
    union { uint i; float f; } v; v.i = ((uint)u) << 16; return v.f;
}

// ---------------- graph setup ----------------

__global__ void count_kernel(const int* __restrict__ dst, int* __restrict__ counts, int E) {
    int e = blockIdx.x * blockDim.x + threadIdx.x;
    if (e < E) atomicAdd(&counts[dst[e]], 1);
}

// exclusive scan counts[n] -> rowstart[n+1], plus dis[i] = rsqrt(deg) fused
__global__ void scan_kernel(const int* __restrict__ counts, int* __restrict__ rowstart,
                            float* __restrict__ dis, int n) {
    __shared__ int sums[1024];
    int t = threadIdx.x;
    int chunk = (n + 1023) / 1024;
    int base = t * chunk;
    int s = 0;
    for (int i = 0; i < chunk; ++i) {
        int idx = base + i;
        if (idx < n) s += counts[idx];
    }
    sums[t] = s;
    __syncthreads();
    for (int off = 1; off < 1024; off <<= 1) {
        int v = (t >= off) ? sums[t - off] : 0;
        __syncthreads();
        sums[t] += v;
        __syncthreads();
    }
    int run = sums[t] - s;
    for (int i = 0; i < chunk; ++i) {
        int idx = base + i;
        if (idx < n) {
            rowstart[idx] = run;
            int c = counts[idx];
            dis[idx] = (c > 0) ? rsqrtf((float)c) : 0.f;
            run += c;
        }
    }
    if (t == 1023) rowstart[n] = sums[1023];
}

// CSR fill with gcn-norm weight computed inline: w = dis[src]*dis[dst]
__global__ void csr_fill_kernel(const int* __restrict__ src, const int* __restrict__ dst,
                                const float* __restrict__ dis, const int* __restrict__ rowstart,
                                int* __restrict__ cursor, int* __restrict__ csr_src,
                                float* __restrict__ csr_w, int E) {
    int e = blockIdx.x * blockDim.x + threadIdx.x;
    if (e < E) {
        int d = dst[e];
        int s = src[e];
        int pos = rowstart[d] + atomicAdd(&cursor[d], 1);
        csr_src[pos] = s;
        csr_w[pos]   = dis[s] * dis[d];
    }
}

// ---------------- fused conversions / weight prep ----------------
// W[4][DIN][DOUT] -> Wp[(hp*DOUT+o)][d]  (bf16, row = stacked output col)
static __device__ __forceinline__ void prep_w_elem(const float* W, ushort* Wp,
                                                   int DIN, int DOUT, int i) {
    int hp  = i / (DIN * DOUT);
    int rem = i - hp * DIN * DOUT;
    int d   = rem / DOUT;
    int o   = rem - d * DOUT;
    Wp[(size_t)(hp * DOUT + o) * DIN + d] = f2bf(W[i]);
}
// W[K][C] -> Wt[C][K]
static __device__ __forceinline__ void prep_wt_elem(const float* W, ushort* Wt,
                                                    int K, int C, int i) {
    int k = i / C, c = i - k * C;
    Wt[(size_t)c * K + k] = f2bf(W[i]);
}

__global__ void prep_all_kernel(const float* __restrict__ x, ushort* __restrict__ xb, int nx,
                                const float* __restrict__ W1, ushort* __restrict__ Wp1,
                                const float* __restrict__ W2, ushort* __restrict__ Wp2,
                                const float* __restrict__ W3, ushort* __restrict__ Wp3,
                                const float* __restrict__ Wf, ushort* __restrict__ Wfb,
                                const float* __restrict__ Wd, ushort* __restrict__ Wdb) {
    const int n1 = 4 * 256 * 128, n2 = 4 * 128 * 128, n3 = 4 * 128 * 64, nf = 64 * 64;
    int i = blockIdx.x * blockDim.x + threadIdx.x;
    if (i < nx) { xb[i] = f2bf(x[i]); return; }
    i -= nx;
    if (i < n1) { prep_w_elem(W1, Wp1, 256, 128, i); return; }
    i -= n1;
    if (i < n2) { prep_w_elem(W2, Wp2, 128, 128, i); return; }
    i -= n2;
    if (i < n3) { prep_w_elem(W3, Wp3, 128, 64, i); return; }
    i -= n3;
    if (i < nf) { prep_wt_elem(Wf, Wfb, 64, 64, i); return; }
    i -= nf;
    if (i < nf) { prep_wt_elem(Wd, Wdb, 64, 64, i); return; }
}

// ---------------- projection GEMM: y_k = A @ W[k]^T (all 4 hops) ------------
// Block: 256 thr = 4 waves, wave w computes hop w's DOUT cols for 32 rows.
// y layout: y + hp*M*DOUT, row-major [M][DOUT]. bias added to hop 0 only.
template <int DIN, int DOUT>
__global__ __launch_bounds__(256) void proj_gemm_kernel(
        const ushort* __restrict__ A, const ushort* __restrict__ Wp,
        const float* __restrict__ bias, ushort* __restrict__ y, int M) {
    constexpr int NJ = DOUT / 16;
    int tid = threadIdx.x, wave = tid >> 6, lane = tid & 63;
    int lr = lane & 15, lk = lane >> 4;
    int r0 = blockIdx.x * 32;
    int ra0 = min(r0 + lr, M - 1);
    int ra1 = min(r0 + 16 + lr, M - 1);

    f32x4 acc[2][NJ];
    #pragma unroll
    for (int mi = 0; mi < 2; ++mi)
        #pragma unroll
        for (int nj = 0; nj < NJ; ++nj)
            acc[mi][nj] = (f32x4){0.f, 0.f, 0.f, 0.f};

    const ushort* a0p = A + (size_t)ra0 * DIN + lk * 8;
    const ushort* a1p = A + (size_t)ra1 * DIN + lk * 8;
    #pragma unroll
    for (int kc = 0; kc < DIN; kc += 32) {
        short8 a0 = *(const short8*)(a0p + kc);
        short8 a1 = *(const short8*)(a1p + kc);
        #pragma unroll
        for (int nj = 0; nj < NJ; ++nj) {
            short8 b = *(const short8*)(Wp + (size_t)(wave * DOUT + nj * 16 + lr) * DIN
                                        + kc + lk * 8);
            acc[0][nj] = __builtin_amdgcn_mfma_f32_16x16x32_bf16(a0, b, acc[0][nj], 0, 0, 0);
            acc[1][nj] = __builtin_amdgcn_mfma_f32_16x16x32_bf16(a1, b, acc[1][nj], 0, 0, 0);
        }
    }

    ushort* yw = y + (size_t)wave * M * DOUT;
    #pragma unroll
    for (int nj = 0; nj < NJ; ++nj) {
        int c = nj * 16 + lr;
        float bv = (wave == 0) ? bias[c] : 0.f;
        #pragma unroll
        for (int mi = 0; mi < 2; ++mi) {
            int rbase = r0 + mi * 16 + lk * 4;
            #pragma unroll
            for (int r = 0; r < 4; ++r) {
                int row = rbase + r;
                if (row < M)
                    yw[(size_t)row * DOUT + c] = f2bf(acc[mi][nj][r] + bv);
            }
        }
    }
}

// ---------------- Horner aggregation step: out = (yk + A*h) [relu] ----------
// wave-per-node, LPE = D/8 lanes per edge (16B/lane), EPI = 64/LPE edges/iter.
template <int D, bool RELU>
__global__ __launch_bounds__(256) void agg5_kernel(
        const ushort* __restrict__ h, const ushort* __restrict__ yk,
        const int* __restrict__ rowstart, const int* __restrict__ csr_src,
        const float* __restrict__ csr_w, ushort* __restrict__ out, int Nn) {
    constexpr int LPE = D / 8;        // 16 (D=128) or 8 (D=64)
    constexpr int EPI = 64 / LPE;     // 4 or 8
    int wave = threadIdx.x >> 6, lane = threadIdx.x & 63;
    int n = blockIdx.x * 4 + wave;
    if (n >= Nn) return;
    int sub = lane / LPE;
    int ll  = lane % LPE;
    int beg = rowstart[n], end = rowstart[n + 1];

    float acc[8];
    #pragma unroll
    for (int v = 0; v < 8; ++v) acc[v] = 0.f;

    for (int j0 = beg; j0 < end; j0 += 64) {
        int take = end - j0;
        if (take > 64) take = 64;
        int s = 0; float w = 0.f;
        if (lane < take) { s = csr_src[j0 + lane]; w = csr_w[j0 + lane]; }
        for (int i = 0; i < take; i += EPI) {
            int e = i + sub;                 // e >= take lanes carry w=0
            float wi = __shfl(w, e);
            int   si = __shfl(s, e);
            short8 hv = *(const short8*)(h + (size_t)si * D + ll * 8);
            #pragma unroll
            for (int v = 0; v < 8; ++v)
                acc[v] = fmaf(wi, bf2f((ushort)hv[v]), acc[v]);
        }
    }
    #pragma unroll
    for (int off = LPE; off < 64; off <<= 1) {
        #pragma unroll
        for (int v = 0; v < 8; ++v) acc[v] += __shfl_xor(acc[v], off);
    }

    if (sub == 0) {
        short8 yv = *(const short8*)(yk + (size_t)n * D + ll * 8);
        short8 o;
        #pragma unroll
        for (int v = 0; v < 8; ++v) {
            float val = acc[v] + bf2f((ushort)yv[v]);
            if (RELU) val = fmaxf(val, 0.f);
            o[v] = (short)f2bf(val);
        }
        *(short8*)(out + (size_t)n * D + ll * 8) = o;
    }
}

// ---------------- fused dual projection: zz = A@Wf^T+bf ; zw = zz@Wd^T ------
__global__ __launch_bounds__(256) void lin64_dual_kernel(
        const ushort* __restrict__ A, const ushort* __restrict__ Wfb,
        const float* __restrict__ bias, const ushort* __restrict__ Wdb,
        ushort* __restrict__ zz, ushort* __restrict__ zw, int M) {
    __shared__ ushort zl[4][32][72];   // +8 ushort pad
    int tid = threadIdx.x, wave = tid >> 6, lane = tid & 63;
    int lr = lane & 15, lk = lane >> 4;
    int r0 = blockIdx.x * 128 + wave * 32;
    int ra0 = min(r0 + lr, M - 1);
    int ra1 = min(r0 + 16 + lr, M - 1);

    short8 a[2][2], b[4][2];
    #pragma unroll
    for (int kc = 0; kc < 2; ++kc) {
        a[0][kc] = *(const short8*)(A + (size_t)ra0 * 64 + kc * 32 + lk * 8);
        a[1][kc] = *(const short8*)(A + (size_t)ra1 * 64 + kc * 32 + lk * 8);
        #pragma unroll
        for (int nj = 0; nj < 4; ++nj)
            b[nj][kc] = *(const short8*)(Wfb + (size_t)(nj * 16 + lr) * 64 + kc * 32 + lk * 8);
    }
    f32x4 acc1[2][4];
    #pragma unroll
    for (int mi = 0; mi < 2; ++mi)
        #pragma unroll
        for (int nj = 0; nj < 4; ++nj) {
            acc1[mi][nj] = (f32x4){0.f, 0.f, 0.f, 0.f};
            acc1[mi][nj] = __builtin_amdgcn_mfma_f32_16x16x32_bf16(a[mi][0], b[nj][0], acc1[mi][nj], 0, 0, 0);
            acc1[mi][nj] = __builtin_amdgcn_mfma_f32_16x16x32_bf16(a[mi][1], b[nj][1], acc1[mi][nj], 0, 0, 0);
        }

    #pragma unroll
    for (int nj = 0; nj < 4; ++nj) {
        int c = nj * 16 + lr;
        float bv = bias[c];
        #pragma unroll
        for (int mi = 0; mi < 2; ++mi) {
            int rloc = mi * 16 + lk * 4;
            #pragma unroll
            for (int r = 0; r < 4; ++r) {
                ushort u = f2bf(acc1[mi][nj][r] + bv);
                zl[wave][rloc + r][c] = u;
                int row = r0 + rloc + r;
                if (row < M) zz[(size_t)row * 64 + c] = u;
            }
        }
    }
    __syncthreads();

    short8 a2[2][2], b2[4][2];
    #pragma unroll
    for (int kc = 0; kc < 2; ++kc) {
        a2[0][kc] = *(const short8*)&zl[wave][lr][kc * 32 + lk * 8];
        a2[1][kc] = *(const short8*)&zl[wave][16 + lr][kc * 32 + lk * 8];
        #pragma unroll
        for (int nj = 0; nj < 4; ++nj)
            b2[nj][kc] = *(const short8*)(Wdb + (size_t)(nj * 16 + lr) * 64 + kc * 32 + lk * 8);
    }
    f32x4 acc2[2][4];
    #pragma unroll
    for (int mi = 0; mi < 2; ++mi)
        #pragma unroll
        for (int nj = 0; nj < 4; ++nj) {
            acc2[mi][nj] = (f32x4){0.f, 0.f, 0.f, 0.f};
            acc2[mi][nj] = __builtin_amdgcn_mfma_f32_16x16x32_bf16(a2[mi][0], b2[nj][0], acc2[mi][nj], 0, 0, 0);
            acc2[mi][nj] = __builtin_amdgcn_mfma_f32_16x16x32_bf16(a2[mi][1], b2[nj][1], acc2[mi][nj], 0, 0, 0);
        }
    #pragma unroll
    for (int nj = 0; nj < 4; ++nj) {
        int c = nj * 16 + lr;
        #pragma unroll
        for (int mi = 0; mi < 2; ++mi) {
            int rbase = r0 + mi * 16 + lk * 4;
            #pragma unroll
            for (int r = 0; r < 4; ++r) {
                int row = rbase + r;
                if (row < M) zw[(size_t)row * 64 + c] = f2bf(acc2[mi][nj][r]);
            }
        }
    }
}

// ---------------- decode: adj = ZW @ Z^T via 32x32x16 MFMA ----------------
__global__ __launch_bounds__(256) void decode32_kernel(
        const ushort* __restrict__ ZW, const ushort* __restrict__ Z,
        float* __restrict__ out, int Nn) {
    int tid = threadIdx.x, wave = tid >> 6, lane = tid & 63;
    int wr = wave >> 1, wc = wave & 1;
    int row0 = blockIdx.y * 128 + wr * 64;
    int col0 = blockIdx.x * 128 + wc * 64;
    int lr = lane & 31, hi = lane >> 5;

    short8 a[2][4], b[2][4];
    #pragma unroll
    for (int mi = 0; mi < 2; ++mi) {
        int ra = min(row0 + mi * 32 + lr, Nn - 1);
        int rb = min(col0 + mi * 32 + lr, Nn - 1);
        const ushort* pa = ZW + (size_t)ra * 64 + hi * 8;
        const ushort* pb = Z  + (size_t)rb * 64 + hi * 8;
        #pragma unroll
        for (int kc = 0; kc < 4; ++kc) {
            a[mi][kc] = *(const short8*)(pa + kc * 16);
            b[mi][kc] = *(const short8*)(pb + kc * 16);
        }
    }

    f32x16 acc[2][2];
    #pragma unroll
    for (int mi = 0; mi < 2; ++mi)
        #pragma unroll
        for (int nj = 0; nj < 2; ++nj) {
            f32x16 c;
            #pragma unroll
            for (int q = 0; q < 16; ++q) c[q] = 0.f;
            #pragma unroll
            for (int kc = 0; kc < 4; ++kc)
                c = __builtin_amdgcn_mfma_f32_32x32x16_bf16(a[mi][kc], b[nj][kc], c, 0, 0, 0);
            acc[mi][nj] = c;
        }

    bool full = (row0 + 64 <= Nn) && (col0 + 64 <= Nn);
    #pragma unroll
    for (int mi = 0; mi < 2; ++mi)
        #pragma unroll
        for (int nj = 0; nj < 2; ++nj) {
            int cb = col0 + nj * 32 + lr;
            #pragma unroll
            for (int reg = 0; reg < 16; ++reg) {
                int row = row0 + mi * 32 + (reg & 3) + 8 * (reg >> 2) + 4 * hi;
                if (full) {
                    __builtin_nontemporal_store(acc[mi][nj][reg], &out[(size_t)row * Nn + cb]);
                } else {
                    if (row < Nn && cb < Nn)
                        __builtin_nontemporal_store(acc[mi][nj][reg], &out[(size_t)row * Nn + cb]);
                }
            }
        }
}

// ---------------- launch ----------------

extern "C" void kernel_launch(void* const* d_in, const int* in_sizes, int n_in,
                              void* d_out, int out_size, void* d_ws, size_t ws_size,
                              hipStream_t stream) {
    const float* x  = (const float*)d_in[0];
    const int*   ei = (const int*)d_in[1];
    const float* W1 = (const float*)d_in[2];
    const float* b1 = (const float*)d_in[3];
    const float* W2 = (const float*)d_in[4];
    const float* b2 = (const float*)d_in[5];
    const float* W3 = (const float*)d_in[6];
    const float* b3 = (const float*)d_in[7];
    const float* Wf = (const float*)d_in[8];
    const float* bf = (const float*)d_in[9];
    const float* Wd = (const float*)d_in[10];

    const int Nn = in_sizes[0] / 256;   // 10000
    const int E  = in_sizes[1] / 2;     // 320000
    const int* src = ei;
    const int* dst = ei + E;

    char* p = (char*)d_ws;
    auto alloc = [&](size_t bytes) -> char* {
        char* r = p;
        p += (bytes + 255) & ~(size_t)255;
        return r;
    };
    size_t nslot = ((size_t)Nn * 4 + 255) & ~(size_t)255;
    int*    counts   = (int*)alloc((size_t)Nn * 4);
    int*    cursor   = (int*)alloc((size_t)Nn * 4);
    int*    rowstart = (int*)alloc((size_t)(Nn + 1) * 4);
    float*  dis      = (float*)alloc((size_t)Nn * 4);
    int*    csr_src  = (int*)alloc((size_t)E * 4);
    float*  csr_w    = (float*)alloc((size_t)E * 4);
    ushort* xb       = (ushort*)alloc((size_t)Nn * 256 * 2);
    ushort* yb       = (ushort*)alloc((size_t)4 * Nn * 128 * 2);  // y[4][Nn][<=128]
    ushort* t1       = (ushort*)alloc((size_t)Nn * 128 * 2);
    ushort* t2       = (ushort*)alloc((size_t)Nn * 128 * 2);
    ushort* out1b    = (ushort*)alloc((size_t)Nn * 128 * 2);
    ushort* out2b    = (ushort*)alloc((size_t)Nn * 128 * 2);
    ushort* out3b    = (ushort*)alloc((size_t)Nn * 64 * 2);
    ushort* zzb      = (ushort*)alloc((size_t)Nn * 64 * 2);
    ushort* zwb      = (ushort*)alloc((size_t)Nn * 64 * 2);
    ushort* Wp1      = (ushort*)alloc((size_t)512 * 256 * 2);
    ushort* Wp2      = (ushort*)alloc((size_t)512 * 128 * 2);
    ushort* Wp3      = (ushort*)alloc((size_t)256 * 128 * 2);
    ushort* Wfb      = (ushort*)alloc((size_t)64 * 64 * 2);
    ushort* Wdb      = (ushort*)alloc((size_t)64 * 64 * 2);

    hipMemsetAsync(counts, 0, nslot + (size_t)Nn * 4, stream);

    int eb = (E + 255) / 256;
    count_kernel<<<eb, 256, 0, stream>>>(dst, counts, E);
    scan_kernel<<<1, 1024, 0, stream>>>(counts, rowstart, dis, Nn);
    csr_fill_kernel<<<eb, 256, 0, stream>>>(src, dst, dis, rowstart, cursor,
                                            csr_src, csr_w, E);

    int nx = Nn * 256;
    int nprep = nx + 4 * 256 * 128 + 4 * 128 * 128 + 4 * 128 * 64 + 64 * 64 + 64 * 64;
    prep_all_kernel<<<(nprep + 255) / 256, 256, 0, stream>>>(
        x, xb, nx, W1, Wp1, W2, Wp2, W3, Wp3, Wf, Wfb, Wd, Wdb);

    int ab = (Nn + 3) / 4;
    int gb = (Nn + 31) / 32;
    size_t Y128 = (size_t)Nn * 128;
    size_t Y64  = (size_t)Nn * 64;

    // ---- layer 1: 256 -> 128 (project, then Horner hops at D=128) ----
    proj_gemm_kernel<256, 128><<<gb, 256, 0, stream>>>(xb, Wp1, b1, yb, Nn);
    agg5_kernel<128, false><<<ab, 256, 0, stream>>>(yb + 3 * Y128, yb + 2 * Y128,
                                                    rowstart, csr_src, csr_w, t1, Nn);
    agg5_kernel<128, false><<<ab, 256, 0, stream>>>(t1, yb + 1 * Y128,
                                                    rowstart, csr_src, csr_w, t2, Nn);
    agg5_kernel<128, true ><<<ab, 256, 0, stream>>>(t2, yb,
                                                    rowstart, csr_src, csr_w, out1b, Nn);

    // ---- layer 2: 128 -> 128 ----
    proj_gemm_kernel<128, 128><<<gb, 256, 0, stream>>>(out1b, Wp2, b2, yb, Nn);
    agg5_kernel<128, false><<<ab, 256, 0, stream>>>(yb + 3 * Y128, yb + 2 * Y128,
                                                    rowstart, csr_src, csr_w, t1, Nn);
    agg5_kernel<128, false><<<ab, 256, 0, stream>>>(t1, yb + 1 * Y128,
                                                    rowstart, csr_src, csr_w, t2, Nn);
    agg5_kernel<128, true ><<<ab, 256, 0, stream>>>(t2, yb,
                                                    rowstart, csr_src, csr_w, out2b, Nn);

    // ---- layer 3: 128 -> 64 (hops at D=64) ----
    proj_gemm_kernel<128, 64><<<gb, 256, 0, stream>>>(out2b, Wp3, b3, yb, Nn);
    agg5_kernel<64, false><<<ab, 256, 0, stream>>>(yb + 3 * Y64, yb + 2 * Y64,
                                                   rowstart, csr_src, csr_w, t1, Nn);
    agg5_kernel<64, false><<<ab, 256, 0, stream>>>(t1, yb + 1 * Y64,
                                                   rowstart, csr_src, csr_w, t2, Nn);
    agg5_kernel<64, true ><<<ab, 256, 0, stream>>>(t2, yb,
                                                   rowstart, csr_src, csr_w, out3b, Nn);

    // ---- zz = h @ Wf + bf ; zw = zz @ Wd (fused) ----
    int lb = (Nn + 127) / 128;
    lin64_dual_kernel<<<lb, 256, 0, stream>>>(out3b, Wfb, bf, Wdb, zzb, zwb, Nn);

    // ---- adj = zw @ z^T ----
    int db = (Nn + 127) / 128;
    decode32_kernel<<<dim3(db, db), 256, 0, stream>>>(zwb, zzb, (float*)d_out, Nn);
}

// Round 7
// 324.048 us; speedup vs baseline: 8.8438x; 1.0255x over previous
//
#include <hip/hip_runtime.h>
#include <hip/hip_bf16.h>
#include <cstdint>
#include <cstddef>

// ---------------------------------------------------------------------------
// GraphAutoEncoder: 3x TAGConv(K=3) + linear + bilinear decode.
// N=10000, E=320000, D: 256 -> 128 -> 128 -> 64.
// Round 6: agg with 2-stage software pipeline + int2-interleaved CSR + 512-thr
// blocks; count fused into prep (region-split, float4 x-convert). 17 kernels.
// ---------------------------------------------------------------------------

typedef __attribute__((ext_vector_type(8)))  short short8;   // 8 bf16
typedef __attribute__((ext_vector_type(4)))  float f32x4;
typedef __attribute__((ext_vector_type(16))) float f32x16;

static __device__ __forceinline__ ushort f2bf(float f) {
    __hip_bfloat16 h = __float2bfloat16(f);
    return *reinterpret_cast<const ushort*>(&h);
}
static __device__ __forceinline__ float bf2f(ushort u) {
    union { uint i; float f; } v; v.i = ((uint)u) << 16; return v.f;
}

// ---------------- setup: count + all weight prep + x->bf16 (fused) ----------

static __device__ __forceinline__ void prep_w_elem(const float* W, ushort* Wp,
                                                   int DIN, int DOUT, int i) {
    int hp  = i / (DIN * DOUT);
    int rem = i - hp * DIN * DOUT;
    int d   = rem / DOUT;
    int o   = rem - d * DOUT;
    Wp[(size_t)(hp * DOUT + o) * DIN + d] = f2bf(W[i]);
}
static __device__ __forceinline__ void prep_wt_elem(const float* W, ushort* Wt,
                                                    int K, int C, int i) {
    int k = i / C, c = i - k * C;
    Wt[(size_t)c * K + k] = f2bf(W[i]);
}

__global__ void setup_kernel(const int* __restrict__ dst, int* __restrict__ counts, int E,
                             const float* __restrict__ x, ushort* __restrict__ xb, int nx4,
                             const float* __restrict__ W1, ushort* __restrict__ Wp1,
                             const float* __restrict__ W2, ushort* __restrict__ Wp2,
                             const float* __restrict__ W3, ushort* __restrict__ Wp3,
                             const float* __restrict__ Wf, ushort* __restrict__ Wfb,
                             const float* __restrict__ Wd, ushort* __restrict__ Wdb) {
    const int n1 = 4 * 256 * 128, n2 = 4 * 128 * 128, n3 = 4 * 128 * 64, nf = 64 * 64;
    int i = blockIdx.x * blockDim.x + threadIdx.x;
    if (i < E) atomicAdd(&counts[dst[i]], 1);
    if (i < nx4) {
        float4 v = ((const float4*)x)[i];
        ushort4 o;
        o.x = f2bf(v.x); o.y = f2bf(v.y); o.z = f2bf(v.z); o.w = f2bf(v.w);
        ((ushort4*)xb)[i] = o;
        return;
    }
    int j = i - nx4;
    if (j < n1) { prep_w_elem(W1, Wp1, 256, 128, j); return; }
    j -= n1;
    if (j < n2) { prep_w_elem(W2, Wp2, 128, 128, j); return; }
    j -= n2;
    if (j < n3) { prep_w_elem(W3, Wp3, 128, 64, j); return; }
    j -= n3;
    if (j < nf) { prep_wt_elem(Wf, Wfb, 64, 64, j); return; }
    j -= nf;
    if (j < nf) { prep_wt_elem(Wd, Wdb, 64, 64, j); return; }
}

// exclusive scan counts[n] -> rowstart[n+1], plus dis[i] = rsqrt(deg) fused
__global__ void scan_kernel(const int* __restrict__ counts, int* __restrict__ rowstart,
                            float* __restrict__ dis, int n) {
    __shared__ int sums[1024];
    int t = threadIdx.x;
    int chunk = (n + 1023) / 1024;
    int base = t * chunk;
    int s = 0;
    for (int i = 0; i < chunk; ++i) {
        int idx = base + i;
        if (idx < n) s += counts[idx];
    }
    sums[t] = s;
    __syncthreads();
    for (int off = 1; off < 1024; off <<= 1) {
        int v = (t >= off) ? sums[t - off] : 0;
        __syncthreads();
        sums[t] += v;
        __syncthreads();
    }
    int run = sums[t] - s;
    for (int i = 0; i < chunk; ++i) {
        int idx = base + i;
        if (idx < n) {
            rowstart[idx] = run;
            int c = counts[idx];
            dis[idx] = (c > 0) ? rsqrtf((float)c) : 0.f;
            run += c;
        }
    }
    if (t == 1023) rowstart[n] = sums[1023];
}

// CSR fill, interleaved int2 (src, float_bits(w)); w = dis[src]*dis[dst]
__global__ void csr_fill_kernel(const int* __restrict__ src, const int* __restrict__ dst,
                                const float* __restrict__ dis, const int* __restrict__ rowstart,
                                int* __restrict__ cursor, int2* __restrict__ csr2, int E) {
    int e = blockIdx.x * blockDim.x + threadIdx.x;
    if (e < E) {
        int d = dst[e];
        int s = src[e];
        int pos = rowstart[d] + atomicAdd(&cursor[d], 1);
        csr2[pos] = make_int2(s, __float_as_int(dis[s] * dis[d]));
    }
}

// ---------------- projection GEMM: y_k = A @ W[k]^T (all 4 hops) ------------
template <int DIN, int DOUT>
__global__ __launch_bounds__(256) void proj_gemm_kernel(
        const ushort* __restrict__ A, const ushort* __restrict__ Wp,
        const float* __restrict__ bias, ushort* __restrict__ y, int M) {
    constexpr int NJ = DOUT / 16;
    int tid = threadIdx.x, wave = tid >> 6, lane = tid & 63;
    int lr = lane & 15, lk = lane >> 4;
    int r0 = blockIdx.x * 32;
    int ra0 = min(r0 + lr, M - 1);
    int ra1 = min(r0 + 16 + lr, M - 1);

    f32x4 acc[2][NJ];
    #pragma unroll
    for (int mi = 0; mi < 2; ++mi)
        #pragma unroll
        for (int nj = 0; nj < NJ; ++nj)
            acc[mi][nj] = (f32x4){0.f, 0.f, 0.f, 0.f};

    const ushort* a0p = A + (size_t)ra0 * DIN + lk * 8;
    const ushort* a1p = A + (size_t)ra1 * DIN + lk * 8;
    #pragma unroll
    for (int kc = 0; kc < DIN; kc += 32) {
        short8 a0 = *(const short8*)(a0p + kc);
        short8 a1 = *(const short8*)(a1p + kc);
        #pragma unroll
        for (int nj = 0; nj < NJ; ++nj) {
            short8 b = *(const short8*)(Wp + (size_t)(wave * DOUT + nj * 16 + lr) * DIN
                                        + kc + lk * 8);
            acc[0][nj] = __builtin_amdgcn_mfma_f32_16x16x32_bf16(a0, b, acc[0][nj], 0, 0, 0);
            acc[1][nj] = __builtin_amdgcn_mfma_f32_16x16x32_bf16(a1, b, acc[1][nj], 0, 0, 0);
        }
    }

    ushort* yw = y + (size_t)wave * M * DOUT;
    #pragma unroll
    for (int nj = 0; nj < NJ; ++nj) {
        int c = nj * 16 + lr;
        float bv = (wave == 0) ? bias[c] : 0.f;
        #pragma unroll
        for (int mi = 0; mi < 2; ++mi) {
            int rbase = r0 + mi * 16 + lk * 4;
            #pragma unroll
            for (int r = 0; r < 4; ++r) {
                int row = rbase + r;
                if (row < M)
                    yw[(size_t)row * DOUT + c] = f2bf(acc[mi][nj][r] + bv);
            }
        }
    }
}

// ---------------- Horner aggregation: out = (yk + A*h) [relu] ---------------
// 512-thr blocks (8 nodes); wave-per-node; 2-stage pipelined gather.
// LPE = D/8 lanes per edge (16B/lane), EPI = 64/LPE edges per iteration.
template <int D, bool RELU>
__global__ __launch_bounds__(512) void agg6_kernel(
        const ushort* __restrict__ h, const ushort* __restrict__ yk,
        const int* __restrict__ rowstart, const int2* __restrict__ csr2,
        ushort* __restrict__ out, int Nn) {
    constexpr int LPE = D / 8;        // 16 (D=128) or 8 (D=64)
    constexpr int EPI = 64 / LPE;     // 4 or 8
    int wave = threadIdx.x >> 6, lane = threadIdx.x & 63;
    int n = blockIdx.x * 8 + wave;
    if (n >= Nn) return;
    int sub = lane / LPE;
    int ll  = lane % LPE;
    int beg = rowstart[n], end = rowstart[n + 1];

    float acc[8];
    #pragma unroll
    for (int v = 0; v < 8; ++v) acc[v] = 0.f;

    for (int j0 = beg; j0 < end; j0 += 64) {
        int take = end - j0;
        if (take > 64) take = 64;
        int2 ed = make_int2(0, 0);
        if (lane < take) ed = csr2[j0 + lane];
        int   s = ed.x;
        float w = __int_as_float(ed.y);
        int tt = (take + EPI - 1) & ~(EPI - 1);

        // stage 0
        float wc = __shfl(w, sub);
        int   sc = __shfl(s, sub);
        short8 hv = *(const short8*)(h + (size_t)sc * D + ll * 8);
        for (int i = EPI; i < tt; i += EPI) {
            float wn = __shfl(w, i + sub);
            int   sn = __shfl(s, i + sub);
            short8 hn = *(const short8*)(h + (size_t)sn * D + ll * 8);
            #pragma unroll
            for (int v = 0; v < 8; ++v)
                acc[v] = fmaf(wc, bf2f((ushort)hv[v]), acc[v]);
            wc = wn; hv = hn;
        }
        #pragma unroll
        for (int v = 0; v < 8; ++v)
            acc[v] = fmaf(wc, bf2f((ushort)hv[v]), acc[v]);
    }

    #pragma unroll
    for (int off = LPE; off < 64; off <<= 1) {
        #pragma unroll
        for (int v = 0; v < 8; ++v) acc[v] += __shfl_xor(acc[v], off);
    }

    if (sub == 0) {
        short8 yv = *(const short8*)(yk + (size_t)n * D + ll * 8);
        short8 o;
        #pragma unroll
        for (int v = 0; v < 8; ++v) {
            float val = acc[v] + bf2f((ushort)yv[v]);
            if (RELU) val = fmaxf(val, 0.f);
            o[v] = (short)f2bf(val);
        }
        *(short8*)(out + (size_t)n * D + ll * 8) = o;
    }
}

// ---------------- fused dual projection: zz = A@Wf^T+bf ; zw = zz@Wd^T ------
__global__ __launch_bounds__(256) void lin64_dual_kernel(
        const ushort* __restrict__ A, const ushort* __restrict__ Wfb,
        const float* __restrict__ bias, const ushort* __restrict__ Wdb,
        ushort* __restrict__ zz, ushort* __restrict__ zw, int M) {
    __shared__ ushort zl[4][32][72];   // +8 ushort pad
    int tid = threadIdx.x, wave = tid >> 6, lane = tid & 63;
    int lr = lane & 15, lk = lane >> 4;
    int r0 = blockIdx.x * 128 + wave * 32;
    int ra0 = min(r0 + lr, M - 1);
    int ra1 = min(r0 + 16 + lr, M - 1);

    short8 a[2][2], b[4][2];
    #pragma unroll
    for (int kc = 0; kc < 2; ++kc) {
        a[0][kc] = *(const short8*)(A + (size_t)ra0 * 64 + kc * 32 + lk * 8);
        a[1][kc] = *(const short8*)(A + (size_t)ra1 * 64 + kc * 32 + lk * 8);
        #pragma unroll
        for (int nj = 0; nj < 4; ++nj)
            b[nj][kc] = *(const short8*)(Wfb + (size_t)(nj * 16 + lr) * 64 + kc * 32 + lk * 8);
    }
    f32x4 acc1[2][4];
    #pragma unroll
    for (int mi = 0; mi < 2; ++mi)
        #pragma unroll
        for (int nj = 0; nj < 4; ++nj) {
            acc1[mi][nj] = (f32x4){0.f, 0.f, 0.f, 0.f};
            acc1[mi][nj] = __builtin_amdgcn_mfma_f32_16x16x32_bf16(a[mi][0], b[nj][0], acc1[mi][nj], 0, 0, 0);
            acc1[mi][nj] = __builtin_amdgcn_mfma_f32_16x16x32_bf16(a[mi][1], b[nj][1], acc1[mi][nj], 0, 0, 0);
        }

    #pragma unroll
    for (int nj = 0; nj < 4; ++nj) {
        int c = nj * 16 + lr;
        float bv = bias[c];
        #pragma unroll
        for (int mi = 0; mi < 2; ++mi) {
            int rloc = mi * 16 + lk * 4;
            #pragma unroll
            for (int r = 0; r < 4; ++r) {
                ushort u = f2bf(acc1[mi][nj][r] + bv);
                zl[wave][rloc + r][c] = u;
                int row = r0 + rloc + r;
                if (row < M) zz[(size_t)row * 64 + c] = u;
            }
        }
    }
    __syncthreads();

    short8 a2[2][2], b2[4][2];
    #pragma unroll
    for (int kc = 0; kc < 2; ++kc) {
        a2[0][kc] = *(const short8*)&zl[wave][lr][kc * 32 + lk * 8];
        a2[1][kc] = *(const short8*)&zl[wave][16 + lr][kc * 32 + lk * 8];
        #pragma unroll
        for (int nj = 0; nj < 4; ++nj)
            b2[nj][kc] = *(const short8*)(Wdb + (size_t)(nj * 16 + lr) * 64 + kc * 32 + lk * 8);
    }
    f32x4 acc2[2][4];
    #pragma unroll
    for (int mi = 0; mi < 2; ++mi)
        #pragma unroll
        for (int nj = 0; nj < 4; ++nj) {
            acc2[mi][nj] = (f32x4){0.f, 0.f, 0.f, 0.f};
            acc2[mi][nj] = __builtin_amdgcn_mfma_f32_16x16x32_bf16(a2[mi][0], b2[nj][0], acc2[mi][nj], 0, 0, 0);
            acc2[mi][nj] = __builtin_amdgcn_mfma_f32_16x16x32_bf16(a2[mi][1], b2[nj][1], acc2[mi][nj], 0, 0, 0);
        }
    #pragma unroll
    for (int nj = 0; nj < 4; ++nj) {
        int c = nj * 16 + lr;
        #pragma unroll
        for (int mi = 0; mi < 2; ++mi) {
            int rbase = r0 + mi * 16 + lk * 4;
            #pragma unroll
            for (int r = 0; r < 4; ++r) {
                int row = rbase + r;
                if (row < M) zw[(size_t)row * 64 + c] = f2bf(acc2[mi][nj][r]);
            }
        }
    }
}

// ---------------- decode: adj = ZW @ Z^T via 32x32x16 MFMA ----------------
__global__ __launch_bounds__(256) void decode32_kernel(
        const ushort* __restrict__ ZW, const ushort* __restrict__ Z,
        float* __restrict__ out, int Nn) {
    int tid = threadIdx.x, wave = tid >> 6, lane = tid & 63;
    int wr = wave >> 1, wc = wave & 1;
    int row0 = blockIdx.y * 128 + wr * 64;
    int col0 = blockIdx.x * 128 + wc * 64;
    int lr = lane & 31, hi = lane >> 5;

    short8 a[2][4], b[2][4];
    #pragma unroll
    for (int mi = 0; mi < 2; ++mi) {
        int ra = min(row0 + mi * 32 + lr, Nn - 1);
        int rb = min(col0 + mi * 32 + lr, Nn - 1);
        const ushort* pa = ZW + (size_t)ra * 64 + hi * 8;
        const ushort* pb = Z  + (size_t)rb * 64 + hi * 8;
        #pragma unroll
        for (int kc = 0; kc < 4; ++kc) {
            a[mi][kc] = *(const short8*)(pa + kc * 16);
            b[mi][kc] = *(const short8*)(pb + kc * 16);
        }
    }

    f32x16 acc[2][2];
    #pragma unroll
    for (int mi = 0; mi < 2; ++mi)
        #pragma unroll
        for (int nj = 0; nj < 2; ++nj) {
            f32x16 c;
            #pragma unroll
            for (int q = 0; q < 16; ++q) c[q] = 0.f;
            #pragma unroll
            for (int kc = 0; kc < 4; ++kc)
                c = __builtin_amdgcn_mfma_f32_32x32x16_bf16(a[mi][kc], b[nj][kc], c, 0, 0, 0);
            acc[mi][nj] = c;
        }

    bool full = (row0 + 64 <= Nn) && (col0 + 64 <= Nn);
    #pragma unroll
    for (int mi = 0; mi < 2; ++mi)
        #pragma unroll
        for (int nj = 0; nj < 2; ++nj) {
            int cb = col0 + nj * 32 + lr;
            #pragma unroll
            for (int reg = 0; reg < 16; ++reg) {
                int row = row0 + mi * 32 + (reg & 3) + 8 * (reg >> 2) + 4 * hi;
                if (full) {
                    __builtin_nontemporal_store(acc[mi][nj][reg], &out[(size_t)row * Nn + cb]);
                } else {
                    if (row < Nn && cb < Nn)
                        __builtin_nontemporal_store(acc[mi][nj][reg], &out[(size_t)row * Nn + cb]);
                }
            }
        }
}

// ---------------- launch ----------------

extern "C" void kernel_launch(void* const* d_in, const int* in_sizes, int n_in,
                              void* d_out, int out_size, void* d_ws, size_t ws_size,
                              hipStream_t stream) {
    const float* x  = (const float*)d_in[0];
    const int*   ei = (const int*)d_in[1];
    const float* W1 = (const float*)d_in[2];
    const float* b1 = (const float*)d_in[3];
    const float* W2 = (const float*)d_in[4];
    const float* b2 = (const float*)d_in[5];
    const float* W3 = (const float*)d_in[6];
    const float* b3 = (const float*)d_in[7];
    const float* Wf = (const float*)d_in[8];
    const float* bf = (const float*)d_in[9];
    const float* Wd = (const float*)d_in[10];

    const int Nn = in_sizes[0] / 256;   // 10000
    const int E  = in_sizes[1] / 2;     // 320000
    const int* src = ei;
    const int* dst = ei + E;

    char* p = (char*)d_ws;
    auto alloc = [&](size_t bytes) -> char* {
        char* r = p;
        p += (bytes + 255) & ~(size_t)255;
        return r;
    };
    size_t nslot = ((size_t)Nn * 4 + 255) & ~(size_t)255;
    int*    counts   = (int*)alloc((size_t)Nn * 4);
    int*    cursor   = (int*)alloc((size_t)Nn * 4);
    int*    rowstart = (int*)alloc((size_t)(Nn + 1) * 4);
    float*  dis      = (float*)alloc((size_t)Nn * 4);
    int2*   csr2     = (int2*)alloc((size_t)E * 8);
    ushort* xb       = (ushort*)alloc((size_t)Nn * 256 * 2);
    ushort* yb       = (ushort*)alloc((size_t)4 * Nn * 128 * 2);  // y[4][Nn][<=128]
    ushort* t1       = (ushort*)alloc((size_t)Nn * 128 * 2);
    ushort* t2       = (ushort*)alloc((size_t)Nn * 128 * 2);
    ushort* out1b    = (ushort*)alloc((size_t)Nn * 128 * 2);
    ushort* out2b    = (ushort*)alloc((size_t)Nn * 128 * 2);
    ushort* out3b    = (ushort*)alloc((size_t)Nn * 64 * 2);
    ushort* zzb      = (ushort*)alloc((size_t)Nn * 64 * 2);
    ushort* zwb      = (ushort*)alloc((size_t)Nn * 64 * 2);
    ushort* Wp1      = (ushort*)alloc((size_t)512 * 256 * 2);
    ushort* Wp2      = (ushort*)alloc((size_t)512 * 128 * 2);
    ushort* Wp3      = (ushort*)alloc((size_t)256 * 128 * 2);
    ushort* Wfb      = (ushort*)alloc((size_t)64 * 64 * 2);
    ushort* Wdb      = (ushort*)alloc((size_t)64 * 64 * 2);

    hipMemsetAsync(counts, 0, nslot + (size_t)Nn * 4, stream);

    // fused count + prep (+ x->bf16 via float4)
    int nx4 = Nn * 256 / 4;
    int nprep = nx4 + 4 * 256 * 128 + 4 * 128 * 128 + 4 * 128 * 64 + 64 * 64 + 64 * 64;
    int nsetup = nprep > E ? nprep : E;
    setup_kernel<<<(nsetup + 255) / 256, 256, 0, stream>>>(
        dst, counts, E, x, xb, nx4,
        W1, Wp1, W2, Wp2, W3, Wp3, Wf, Wfb, Wd, Wdb);

    scan_kernel<<<1, 1024, 0, stream>>>(counts, rowstart, dis, Nn);

    int eb = (E + 255) / 256;
    csr_fill_kernel<<<eb, 256, 0, stream>>>(src, dst, dis, rowstart, cursor, csr2, E);

    int ab = (Nn + 7) / 8;              // agg blocks (8 nodes, 512 thr)
    int gb = (Nn + 31) / 32;
    size_t Y128 = (size_t)Nn * 128;
    size_t Y64  = (size_t)Nn * 64;

    // ---- layer 1: 256 -> 128 (project, then Horner hops at D=128) ----
    proj_gemm_kernel<256, 128><<<gb, 256, 0, stream>>>(xb, Wp1, b1, yb, Nn);
    agg6_kernel<128, false><<<ab, 512, 0, stream>>>(yb + 3 * Y128, yb + 2 * Y128,
                                                    rowstart, csr2, t1, Nn);
    agg6_kernel<128, false><<<ab, 512, 0, stream>>>(t1, yb + 1 * Y128,
                                                    rowstart, csr2, t2, Nn);
    agg6_kernel<128, true ><<<ab, 512, 0, stream>>>(t2, yb,
                                                    rowstart, csr2, out1b, Nn);

    // ---- layer 2: 128 -> 128 ----
    proj_gemm_kernel<128, 128><<<gb, 256, 0, stream>>>(out1b, Wp2, b2, yb, Nn);
    agg6_kernel<128, false><<<ab, 512, 0, stream>>>(yb + 3 * Y128, yb + 2 * Y128,
                                                    rowstart, csr2, t1, Nn);
    agg6_kernel<128, false><<<ab, 512, 0, stream>>>(t1, yb + 1 * Y128,
                                                    rowstart, csr2, t2, Nn);
    agg6_kernel<128, true ><<<ab, 512, 0, stream>>>(t2, yb,
                                                    rowstart, csr2, out2b, Nn);

    // ---- layer 3: 128 -> 64 (hops at D=64) ----
    proj_gemm_kernel<128, 64><<<gb, 256, 0, stream>>>(out2b, Wp3, b3, yb, Nn);
    agg6_kernel<64, false><<<ab, 512, 0, stream>>>(yb + 3 * Y64, yb + 2 * Y64,
                                                   rowstart, csr2, t1, Nn);
    agg6_kernel<64, false><<<ab, 512, 0, stream>>>(t1, yb + 1 * Y64,
                                                   rowstart, csr2, t2, Nn);
    agg6_kernel<64, true ><<<ab, 512, 0, stream>>>(t2, yb,
                                                   rowstart, csr2, out3b, Nn);

    // ---- zz = h @ Wf + bf ; zw = zz @ Wd (fused) ----
    int lb = (Nn + 127) / 128;
    lin64_dual_kernel<<<lb, 256, 0, stream>>>(out3b, Wfb, bf, Wdb, zzb, zwb, Nn);

    // ---- adj = zw @ z^T ----
    int db = (Nn + 127) / 128;
    decode32_kernel<<<dim3(db, db), 256, 0, stream>>>(zwb, zzb, (float*)d_out, Nn);
}